// Round 7
// baseline (267.532 us; speedup 1.0000x reference)
//
#include <hip/hip_runtime.h>
#include <math.h>

// Problem constants
#define NB 4      // batch
#define C  128    // channels (q/k/v/out)
#define CCH 256   // context channels
#define HH 64
#define WW 64
#define NN 4096   // HH*WW
#define HC 32
#define WC 32
#define PP 66     // padded spatial dim for conv input (64 + 2 halo)
#define LOG2E 1.44269504088896f

typedef unsigned short u16;
typedef unsigned int uint32;
typedef short s16x8 __attribute__((ext_vector_type(8)));    // 8 bf16 = MFMA A/B frag
typedef float f32x4 __attribute__((ext_vector_type(4)));    // 16x16 MFMA C/D frag
typedef float f32x16 __attribute__((ext_vector_type(16)));  // 32x32 MFMA C/D frag

// fp32 -> bf16 round-to-nearest-even
__device__ __forceinline__ u16 f2bf(float f) {
    uint32 u = __float_as_uint(f);
    u += 0x7fffu + ((u >> 16) & 1u);
    return (u16)(u >> 16);
}

// ---------------------------------------------------------------------------
// 1) Fused bilinear 2x upsample + transpose-cast: ctx f32 [b][cc][32][32]
//    -> ctx_t bf16 [b][n][cc].
// ---------------------------------------------------------------------------
__global__ __launch_bounds__(256) void upsample_t(const float* __restrict__ ctx,
                                                  u16* __restrict__ ctx_t) {
    __shared__ float ls[2][32][130];
    int y = blockIdx.x;
    int cch = blockIdx.y;
    int b = blockIdx.z;
    float sy = y * 0.5f - 0.25f;
    int y0 = (int)floorf(sy);
    float wy = sy - (float)y0;
    int y0c = y0 < 0 ? 0 : y0;
    int y1c = (y0 + 1 > HC - 1) ? HC - 1 : y0 + 1;
    int tid = threadIdx.x;
#pragma unroll
    for (int t = 0; t < 4; t++) {
        int CI = t * 256 + tid;
        int cc = CI >> 3, xq = CI & 7;
        const float* s = ctx + (size_t)(b * CCH + cch * 128 + cc) * (HC * WC);
        float4 v0 = *(const float4*)(s + y0c * WC + xq * 4);
        float4 v1 = *(const float4*)(s + y1c * WC + xq * 4);
        ls[0][xq * 4 + 0][cc] = v0.x; ls[0][xq * 4 + 1][cc] = v0.y;
        ls[0][xq * 4 + 2][cc] = v0.z; ls[0][xq * 4 + 3][cc] = v0.w;
        ls[1][xq * 4 + 0][cc] = v1.x; ls[1][xq * 4 + 1][cc] = v1.y;
        ls[1][xq * 4 + 2][cc] = v1.z; ls[1][xq * 4 + 3][cc] = v1.w;
    }
    __syncthreads();
    int occ = tid & 127, xh = tid >> 7;
    u16* ob = ctx_t + ((size_t)b * NN + (size_t)y * 64) * CCH + cch * 128 + occ;
    float wy1 = 1.f - wy;
#pragma unroll
    for (int xi = 0; xi < 32; xi++) {
        int x = xi * 2 + xh;
        float sx = x * 0.5f - 0.25f;
        int x0 = (int)floorf(sx);
        float wx = sx - (float)x0;
        int x0c = x0 < 0 ? 0 : x0;
        int x1c = (x0 + 1 > WC - 1) ? WC - 1 : x0 + 1;
        float v00 = ls[0][x0c][occ], v01 = ls[0][x1c][occ];
        float v10 = ls[1][x0c][occ], v11 = ls[1][x1c][occ];
        float val = wy1 * ((1.f - wx) * v00 + wx * v01)
                  + wy  * ((1.f - wx) * v10 + wx * v11);
        ob[(size_t)x * CCH] = f2bf(val);
    }
}

// ---------------------------------------------------------------------------
// 2) Transpose-cast: sr f32 [b][C][NN] -> sr_t bf16 [b][NN][C]
// ---------------------------------------------------------------------------
__global__ __launch_bounds__(256) void tcast(const float* __restrict__ in,
                                             u16* __restrict__ out, int Cin) {
    __shared__ float ls[64 * 65];
    int b = blockIdx.z;
    int ci0 = blockIdx.y * 64;
    int n0 = blockIdx.x * 64;
    int tid = threadIdx.x;
    const float* inb = in + ((size_t)b * Cin + ci0) * NN + n0;
#pragma unroll
    for (int L = 0; L < 4; L++) {
        int fc = tid + L * 256;
        int nc = fc & 15, ci = fc >> 4;
        float4 v = *(const float4*)(inb + (size_t)ci * NN + nc * 4);
        float* d = &ls[ci * 65 + nc * 4];
        d[0] = v.x; d[1] = v.y; d[2] = v.z; d[3] = v.w;
    }
    __syncthreads();
    u16* ob = out + ((size_t)b * NN + n0) * Cin + ci0;
#pragma unroll
    for (int j = 0; j < 16; j++) {
        int o = tid + j * 256;
        int ci = o & 63, n = o >> 6;
        ob[(size_t)n * Cin + ci] = f2bf(ls[ci * 65 + n]);
    }
}

// ---------------------------------------------------------------------------
// 3) Weight prep: Wq (scaled by log2e!) |Wk|Wv -> w_bf; Wp -> wt
// ---------------------------------------------------------------------------
__global__ __launch_bounds__(256) void wprep_all(const float* __restrict__ Wq,
                                                 const float* __restrict__ Wk,
                                                 const float* __restrict__ Wv,
                                                 const float* __restrict__ Wp,
                                                 u16* __restrict__ wbf,
                                                 u16* __restrict__ wt) {
    int i = blockIdx.x * 256 + threadIdx.x;
    if (i < 81920) {
        float v;
        if (i < 16384) v = Wq[i] * LOG2E;     // fold log2e so flash uses exp2
        else if (i < 49152) v = Wk[i - 16384];
        else v = Wv[i - 49152];
        wbf[i] = f2bf(v);
    } else {
        int idx = i - 81920;
        int ciin = idx & 31;
        int co = (idx >> 5) & 127;
        int cb = (idx >> 12) & 3;
        int pos = idx >> 14;
        int ky = pos / 3, kx = pos - ky * 3;
        int ci = cb * 32 + ciin;
        wt[idx] = f2bf(Wp[((size_t)(co * C + ci) * 3 + ky) * 3 + kx]);
    }
}

// ---------------------------------------------------------------------------
// 4) Zero att_t + acc + lacc (ws poisoned every call)
// ---------------------------------------------------------------------------
__global__ __launch_bounds__(256) void zero_all(uint4* __restrict__ att,
                                                uint4* __restrict__ acc) {
    int i = blockIdx.x * 256 + threadIdx.x;
    if (i < 278784) att[i] = make_uint4(0, 0, 0, 0);
    else acc[i - 278784] = make_uint4(0, 0, 0, 0);
}

// ---------------------------------------------------------------------------
// 5) Fused projection GEMM (q/k/v by blockIdx.z), LDS-staged. (r6, proven)
// ---------------------------------------------------------------------------
__global__ __launch_bounds__(256) void proj_all(const u16* __restrict__ sr_t,
                                                const u16* __restrict__ ctx_t,
                                                const u16* __restrict__ wbf,
                                                const float* __restrict__ bq,
                                                const float* __restrict__ bk,
                                                const float* __restrict__ bv,
                                                u16* __restrict__ q_t,
                                                u16* __restrict__ k_t,
                                                u16* __restrict__ v_bf) {
    __shared__ u16 xs[128 * 64];
    __shared__ u16 wsm[128 * 64];
    int z = blockIdx.z;
    int b = blockIdx.y;
    int n0 = blockIdx.x * 128;
    int Cin = (z == 0) ? C : CCH;
    const u16* xb = (z == 0 ? sr_t : ctx_t) + (size_t)b * NN * Cin;
    const u16* wb = wbf + (z == 0 ? 0 : (z == 1 ? 16384 : 49152));
    const float* bias = (z == 0) ? bq : (z == 1 ? bk : bv);
    float bsc = (z == 0) ? LOG2E : 1.0f;     // bias of q also scaled
    bool vmode = (z == 2);

    int tid = threadIdx.x;
    int w = tid >> 6, lane = tid & 63, l31 = lane & 31, half = lane >> 5;
    int xh = w >> 1, wh = w & 1;

    f32x16 acc[2][2];
#pragma unroll
    for (int xt = 0; xt < 2; xt++)
#pragma unroll
        for (int wt2 = 0; wt2 < 2; wt2++)
#pragma unroll
            for (int i = 0; i < 16; i++) acc[xt][wt2][i] = 0.f;

    int nchunks = Cin >> 6;
    for (int c0i = 0; c0i < nchunks; c0i++) {
        int c0 = c0i * 64;
        __syncthreads();
#pragma unroll
        for (int t = 0; t < 4; t++) {
            int CI = t * 256 + tid;
            int row = CI >> 3, sl = CI & 7;
            int lc = sl ^ (row & 7);
            __builtin_amdgcn_global_load_lds(
                (const __attribute__((address_space(1))) void*)(xb + (size_t)(n0 + row) * Cin + c0 + lc * 8),
                (__attribute__((address_space(3))) void*)&xs[(size_t)CI * 8], 16, 0, 0);
        }
#pragma unroll
        for (int t = 0; t < 4; t++) {
            int CI = t * 256 + tid;
            int co = CI >> 3, sl = CI & 7;
            int lc = sl ^ (co & 7);
            __builtin_amdgcn_global_load_lds(
                (const __attribute__((address_space(1))) void*)(wb + (size_t)co * Cin + c0 + lc * 8),
                (__attribute__((address_space(3))) void*)&wsm[(size_t)CI * 8], 16, 0, 0);
        }
        __syncthreads();
#pragma unroll
        for (int kg = 0; kg < 4; kg++) {
            int pc = ((kg * 2 + half) ^ (l31 & 7)) * 8;
            s16x8 xf[2], wf2[2];
#pragma unroll
            for (int xt = 0; xt < 2; xt++)
                xf[xt] = *(const s16x8*)&xs[(xh * 64 + xt * 32 + l31) * 64 + pc];
#pragma unroll
            for (int wt2 = 0; wt2 < 2; wt2++)
                wf2[wt2] = *(const s16x8*)&wsm[(wh * 64 + wt2 * 32 + l31) * 64 + pc];
#pragma unroll
            for (int xt = 0; xt < 2; xt++)
#pragma unroll
                for (int wt2 = 0; wt2 < 2; wt2++) {
                    if (vmode)
                        acc[xt][wt2] = __builtin_amdgcn_mfma_f32_32x32x16_bf16(wf2[wt2], xf[xt], acc[xt][wt2], 0, 0, 0);
                    else
                        acc[xt][wt2] = __builtin_amdgcn_mfma_f32_32x32x16_bf16(xf[xt], wf2[wt2], acc[xt][wt2], 0, 0, 0);
                }
        }
    }

    if (!vmode) {
        u16* ot = (z == 0 ? q_t : k_t) + (size_t)b * NN * C;
        float bv2[2];
#pragma unroll
        for (int wt2 = 0; wt2 < 2; wt2++) bv2[wt2] = bias[wh * 64 + wt2 * 32 + l31] * bsc;
#pragma unroll
        for (int xt = 0; xt < 2; xt++)
#pragma unroll
            for (int r = 0; r < 16; r++) {
                int n = n0 + xh * 64 + xt * 32 + (r & 3) + 8 * (r >> 2) + 4 * half;
#pragma unroll
                for (int wt2 = 0; wt2 < 2; wt2++)
                    ot[(size_t)n * C + wh * 64 + wt2 * 32 + l31] = f2bf(acc[xt][wt2][r] + bv2[wt2]);
            }
    } else {
        u16* ov = v_bf + (size_t)b * C * NN;
#pragma unroll
        for (int wt2 = 0; wt2 < 2; wt2++)
#pragma unroll
            for (int r = 0; r < 16; r++) {
                int co = wh * 64 + wt2 * 32 + (r & 3) + 8 * (r >> 2) + 4 * half;
                float bvv = bias[co];
#pragma unroll
                for (int xt = 0; xt < 2; xt++) {
                    int n = n0 + xh * 64 + xt * 32 + l31;
                    ov[(size_t)co * NN + n] = f2bf(acc[xt][wt2][r] + bvv);
                }
            }
    }
}

// ---------------------------------------------------------------------------
// 6) Flash attention v7: double-buffered K/V (1 barrier/iter), 2 q-tiles per
//    wave (K/V frag reads feed 2 MFMAs), P-transpose via __shfl_xor(32) in
//    registers (zero P LDS traffic), exp2 (Q pre-scaled by log2e).
//    Block 256 thr = 4 waves x 64q = 256 q. Split-K x8. Grid 512. LDS 64 KB.
// ---------------------------------------------------------------------------
__global__ __launch_bounds__(256, 2) void flash_mfma(const u16* __restrict__ qt_p,
                                                     const u16* __restrict__ kt_p,
                                                     const u16* __restrict__ vt_p,
                                                     float* __restrict__ acc,
                                                     float* __restrict__ lacc) {
    __shared__ u16 ks[2][64 * 128];   // [key][ch] chunk-XOR16, 2x16 KB
    __shared__ u16 vs[2][128 * 64];   // [ch][key] chunk-XOR8,  2x16 KB

    int ib = blockIdx.x;
    int b = (ib & 7) >> 1;                       // batch -> XCD pair
    int rest = ((ib >> 3) << 1) | (ib & 1);      // 0..127
    int qblk = rest >> 3;                        // 0..15
    int split = rest & 7;
    int tid = threadIdx.x;
    int w = tid >> 6, lane = tid & 63, l31 = lane & 31, half = lane >> 5;
    int n0 = qblk * 256 + w * 64;                // wave covers 64 q

    const u16* qtb = qt_p + (size_t)b * NN * C;
    const u16* ktb = kt_p + (size_t)b * NN * C;
    const u16* vtb = vt_p + (size_t)b * C * NN;

    auto stageK = [&](int buf, int m0) {
#pragma unroll
        for (int t = 0; t < 4; t++) {
            int CI = (w * 4 + t) * 64 + lane;
            int r = CI >> 4;
            int lc = (CI & 15) ^ (r & 15);
            __builtin_amdgcn_global_load_lds(
                (const __attribute__((address_space(1))) void*)(ktb + (size_t)(m0 + r) * C + lc * 8),
                (__attribute__((address_space(3))) void*)&ks[buf][(w * 4 + t) * 512], 16, 0, 0);
        }
    };
    auto stageV = [&](int buf, int m0) {
#pragma unroll
        for (int t = 0; t < 4; t++) {
            int CI = (w * 4 + t) * 64 + lane;
            int c = CI >> 3;
            int lc = (CI & 7) ^ (c & 7);
            __builtin_amdgcn_global_load_lds(
                (const __attribute__((address_space(1))) void*)(vtb + (size_t)c * NN + m0 + lc * 8),
                (__attribute__((address_space(3))) void*)&vs[buf][(w * 4 + t) * 512], 16, 0, 0);
        }
    };

    // Q B-fragments in registers: 2 q-tiles x 8 ch-groups
    s16x8 qf[2][8];
#pragma unroll
    for (int qt2 = 0; qt2 < 2; qt2++)
#pragma unroll
        for (int kg = 0; kg < 8; kg++)
            qf[qt2][kg] = *(const s16x8*)(qtb + (size_t)(n0 + qt2 * 32 + l31) * C + kg * 16 + half * 8);

    f32x16 oacc[2][4];
#pragma unroll
    for (int qt2 = 0; qt2 < 2; qt2++)
#pragma unroll
        for (int mt = 0; mt < 4; mt++)
#pragma unroll
            for (int i = 0; i < 16; i++) oacc[qt2][mt][i] = 0.f;
    float lsum[2] = {0.f, 0.f};

    int m_base = split * 512;
    stageK(0, m_base);
    stageV(0, m_base);
    __syncthreads();

    for (int it = 0; it < 8; it++) {
        int cur = it & 1;
        if (it < 7) {                             // prefetch next into other buf
            stageK(cur ^ 1, m_base + it * 64 + 64);
            stageV(cur ^ 1, m_base + it * 64 + 64);
        }
        const u16* ksb = &ks[cur][0];
        const u16* vsb = &vs[cur][0];

#pragma unroll
        for (int qt2 = 0; qt2 < 2; qt2++) {
            // ---- S^T = K·Q : 2 key-tiles of 32, K-frag shared across q-tiles
            f32x16 st[2];
#pragma unroll
            for (int kmt = 0; kmt < 2; kmt++)
#pragma unroll
                for (int i = 0; i < 16; i++) st[kmt][i] = 0.f;
#pragma unroll
            for (int kg = 0; kg < 8; kg++) {
                int pc = ((kg * 2 + half) ^ (l31 & 15)) * 8;
#pragma unroll
                for (int kmt = 0; kmt < 2; kmt++) {
                    s16x8 kf = *(const s16x8*)&ksb[(kmt * 32 + l31) * 128 + pc];
                    st[kmt] = __builtin_amdgcn_mfma_f32_32x32x16_bf16(kf, qf[qt2][kg], st[kmt], 0, 0, 0);
                }
            }
            // ---- exp2 + register P-transpose (shfl_xor 32) + PV ----
#pragma unroll
            for (int kmt = 0; kmt < 2; kmt++) {
                float e[16];
                float ls = 0.f;
#pragma unroll
                for (int r = 0; r < 16; r++) { e[r] = exp2f(st[kmt][r]); ls += e[r]; }
                lsum[qt2] += ls;
                uint32 A[4], B4[4];
#pragma unroll
                for (int g = 0; g < 4; g++) {
                    A[g]  = __builtin_amdgcn_perm(__float_as_uint(e[4 * g + 1]), __float_as_uint(e[4 * g + 0]), 0x07060302u);
                    B4[g] = __builtin_amdgcn_perm(__float_as_uint(e[4 * g + 3]), __float_as_uint(e[4 * g + 2]), 0x07060302u);
                }
#pragma unroll
                for (int s = 0; s < 2; s++) {
                    // lane needs own group (2s+half) and partner's (2s+half);
                    // partner needs group (2s+1-half) -> send that one.
                    uint32 sendA = half ? A[2 * s] : A[2 * s + 1];
                    uint32 sendB = half ? B4[2 * s] : B4[2 * s + 1];
                    uint32 rA = __shfl_xor(sendA, 32);
                    uint32 rB = __shfl_xor(sendB, 32);
                    uint32 oA = half ? A[2 * s + 1] : A[2 * s];
                    uint32 oB = half ? B4[2 * s + 1] : B4[2 * s];
                    union { uint32 u[4]; s16x8 v; } pu;
                    pu.u[0] = half ? rA : oA;
                    pu.u[1] = half ? rB : oB;
                    pu.u[2] = half ? oA : rA;
                    pu.u[3] = half ? oB : rB;
                    s16x8 pf = pu.v;
                    int kgp = kmt * 2 + s;
                    int pcv = ((kgp * 2 + half) ^ (l31 & 7)) * 8;
#pragma unroll
                    for (int mt = 0; mt < 4; mt++) {
                        s16x8 vf = *(const s16x8*)&vsb[(mt * 32 + l31) * 64 + pcv];
                        oacc[qt2][mt] = __builtin_amdgcn_mfma_f32_32x32x16_bf16(vf, pf, oacc[qt2][mt], 0, 0, 0);
                    }
                }
            }
        }
        __syncthreads();   // all waves done with buf cur; next iter's staging may overwrite
    }

    // ---- epilogue: lsum across halves; coalesced atomic adds ----
#pragma unroll
    for (int qt2 = 0; qt2 < 2; qt2++) {
        float lt = lsum[qt2] + __shfl_xor(lsum[qt2], 32);
        if (half == 0) atomicAdd(&lacc[(size_t)b * NN + n0 + qt2 * 32 + l31], lt);
    }
    float* ab = acc + (size_t)b * C * NN;
#pragma unroll
    for (int qt2 = 0; qt2 < 2; qt2++)
#pragma unroll
        for (int mt = 0; mt < 4; mt++)
#pragma unroll
            for (int r = 0; r < 16; r++) {
                int c = mt * 32 + (r & 3) + 8 * (r >> 2) + 4 * half;
                atomicAdd(&ab[(size_t)c * NN + n0 + qt2 * 32 + l31], oacc[qt2][mt][r]);
            }
}

// ---------------------------------------------------------------------------
// 7) Combine: att_t[b][y+1][x+1][c] = bf16( acc[b][c][n] / lacc[b][n] )
// ---------------------------------------------------------------------------
__global__ __launch_bounds__(256) void flash_combine(const float* __restrict__ acc,
                                                     const float* __restrict__ lacc,
                                                     u16* __restrict__ att_t) {
    __shared__ u16 ts[128 * 66];
    __shared__ float linv[64];
    int b = blockIdx.y;
    int nt = blockIdx.x;
    int n0 = nt * 64;
    int tid = threadIdx.x;
    if (tid < 64) linv[tid] = 1.0f / lacc[(size_t)b * NN + n0 + tid];
    __syncthreads();
    const float* ab = acc + (size_t)b * C * NN + n0;
#pragma unroll
    for (int j = 0; j < 32; j++) {
        int e = tid + j * 256;
        int n = e & 63, c = e >> 6;
        ts[c * 66 + n] = f2bf(ab[(size_t)c * NN + n] * linv[n]);
    }
    __syncthreads();
    u16* ob = att_t + ((size_t)b * PP * PP + (size_t)(nt + 1) * PP + 1) * C;
#pragma unroll
    for (int j = 0; j < 32; j++) {
        int o = tid + j * 256;
        int c = o & 127, n = o >> 7;
        ob[(size_t)n * C + c] = ts[c * 66 + n];
    }
}

// ---------------------------------------------------------------------------
// 8) Implicit-GEMM MFMA conv3x3 + residual. v2: px-split (grid 512, 2/CU),
//    weight frags hoisted per cib (18 b128 loads batched -> one L2 latency).
// ---------------------------------------------------------------------------
__global__ __launch_bounds__(256) void conv3x3_mfma(const u16* __restrict__ att_t,
                                                    const u16* __restrict__ wt,
                                                    const float* __restrict__ bp,
                                                    const float* __restrict__ sr,
                                                    const float* __restrict__ gamma,
                                                    float* __restrict__ out) {
    __shared__ u16 in_s[2][4 * 102 * 8];   // per buf: 4 planes x (3*34) chunks x 16B
    int ib = blockIdx.x;
    int b = (ib & 7) >> 1;
    int rr = ((ib >> 3) << 1) | (ib & 1);  // 0..127
    int y = rr >> 1;                       // output row 0..63
    int x0 = (rr & 1) * 32;                // px half
    int tid = threadIdx.x;
    int w = tid >> 6, lane = tid & 63, l = tid & 15, quad = (tid >> 4) & 3;
    const u16* ab = att_t + (size_t)b * (PP * PP * C);

    auto stage = [&](int cib, int bufi) {
        u16* base = &in_s[bufi][w * 102 * 8];
        const u16* gsrc = ab + cib * 32 + w * 8;
#pragma unroll
        for (int t = 0; t < 2; t++) {
            int idx = t * 64 + lane;              // valid < 102
            int r = idx / 34, xp = idx - r * 34;
            if (t == 0 || lane < 38)
                __builtin_amdgcn_global_load_lds(
                    (const __attribute__((address_space(1))) void*)(gsrc + (size_t)((y + r) * PP + x0 + xp) * C),
                    (__attribute__((address_space(3))) void*)(base + (size_t)t * 64 * 8), 16, 0, 0);
        }
    };

    f32x4 accr[2][2];   // [cf][nf]
#pragma unroll
    for (int cf = 0; cf < 2; cf++)
#pragma unroll
        for (int nf = 0; nf < 2; nf++) accr[cf][nf] = (f32x4){0.f, 0.f, 0.f, 0.f};
    int cow = w * 32;

    stage(0, 0);
    __syncthreads();
#pragma unroll
    for (int cib = 0; cib < 4; cib++) {
        if (cib < 3) stage(cib + 1, (cib + 1) & 1);
        // hoist all 18 weight fragments for this cib (batched L2 loads)
        s16x8 wf[9][2];
#pragma unroll
        for (int pos = 0; pos < 9; pos++)
#pragma unroll
            for (int cf = 0; cf < 2; cf++)
                wf[pos][cf] = *(const s16x8*)&wt[((size_t)(pos * 4 + cib) * C + cow + cf * 16 + l) * 32 + quad * 8];
        const u16* bufc = &in_s[cib & 1][0];
#pragma unroll
        for (int ky = 0; ky < 3; ky++)
#pragma unroll
            for (int kx = 0; kx < 3; kx++) {
                int pos = ky * 3 + kx;
#pragma unroll
                for (int nf = 0; nf < 2; nf++) {
                    s16x8 inf = *(const s16x8*)&bufc[(quad * 102 + ky * 34 + nf * 16 + l + kx) * 8];
                    accr[0][nf] = __builtin_amdgcn_mfma_f32_16x16x32_bf16(wf[pos][0], inf, accr[0][nf], 0, 0, 0);
                    accr[1][nf] = __builtin_amdgcn_mfma_f32_16x16x32_bf16(wf[pos][1], inf, accr[1][nf], 0, 0, 0);
                }
            }
        __syncthreads();
    }

    float g = gamma[0];
    float* ob = out + (size_t)b * C * NN;
    const float* sb = sr + (size_t)b * C * NN;
#pragma unroll
    for (int cf = 0; cf < 2; cf++)
#pragma unroll
        for (int r = 0; r < 4; r++) {
            int co = cow + cf * 16 + quad * 4 + r;
            float bias = bp[co];
#pragma unroll
            for (int nf = 0; nf < 2; nf++) {
                size_t oo = (size_t)co * NN + y * 64 + x0 + nf * 16 + l;
                ob[oo] = sb[oo] + g * (accr[cf][nf][r] + bias);
            }
        }
}

// ---------------------------------------------------------------------------
extern "C" void kernel_launch(void* const* d_in, const int* in_sizes, int n_in,
                              void* d_out, int out_size, void* d_ws, size_t ws_size,
                              hipStream_t stream) {
    const float* sr    = (const float*)d_in[0];
    const float* ctx   = (const float*)d_in[1];
    const float* Wq    = (const float*)d_in[2];
    const float* bq    = (const float*)d_in[3];
    const float* Wk    = (const float*)d_in[4];
    const float* bk    = (const float*)d_in[5];
    const float* Wv    = (const float*)d_in[6];
    const float* bv    = (const float*)d_in[7];
    const float* Wp    = (const float*)d_in[8];
    const float* bp    = (const float*)d_in[9];
    const float* gamma = (const float*)d_in[10];
    float* out = (float*)d_out;

    char* wsb = (char*)d_ws;
    u16*   att_t  = (u16*)wsb;
    float* acc    = (float*)(wsb + (5u << 20));
    float* lacc   = acc + (size_t)NB * C * NN;
    u16*   ctx_t  = (u16*)(wsb + (14u << 20));
    u16*   sr_t   = (u16*)(wsb + (22u << 20));
    u16*   q_t    = (u16*)(wsb + (26u << 20));
    u16*   k_t    = (u16*)(wsb + (30u << 20));
    u16*   v_bf   = (u16*)(wsb + (34u << 20));
    u16*   wt     = (u16*)(wsb + (38u << 20));
    u16*   w_bf   = (u16*)(wsb + (38u << 20) + (512u << 10));

    upsample_t<<<dim3(64, 2, NB), 256, 0, stream>>>(ctx, ctx_t);
    tcast<<<dim3(64, 2, NB), 256, 0, stream>>>(sr, sr_t, C);
    wprep_all<<<dim3(896), 256, 0, stream>>>(Wq, Wk, Wv, Wp, w_bf, wt);
    zero_all<<<dim3(3153), 256, 0, stream>>>((uint4*)att_t, (uint4*)acc);
    proj_all<<<dim3(32, NB, 3), 256, 0, stream>>>(sr_t, ctx_t, w_bf, bq, bk, bv,
                                                  q_t, k_t, v_bf);
    flash_mfma<<<dim3(512), 256, 0, stream>>>(q_t, k_t, v_bf, acc, lacc);
    flash_combine<<<dim3(64, NB), 256, 0, stream>>>(acc, lacc, att_t);
    conv3x3_mfma<<<dim3(512), 256, 0, stream>>>(att_t, wt, bp, sr, gamma, out);
}

// Round 8
// 208.260 us; speedup vs baseline: 1.2846x; 1.2846x over previous
//
#include <hip/hip_runtime.h>
#include <math.h>

// Problem constants
#define NB 4      // batch
#define C  128    // channels (q/k/v/out)
#define CCH 256   // context channels
#define HH 64
#define WW 64
#define NN 4096   // HH*WW
#define HC 32
#define WC 32
#define PP 66     // padded spatial dim for conv input (64 + 2 halo)
#define LOG2E 1.44269504088896f

typedef unsigned short u16;
typedef unsigned int uint32;
typedef short s16x8 __attribute__((ext_vector_type(8)));    // 8 bf16 = MFMA A/B frag
typedef float f32x4 __attribute__((ext_vector_type(4)));    // 16x16 MFMA C/D frag
typedef float f32x16 __attribute__((ext_vector_type(16)));  // 32x32 MFMA C/D frag

// fp32 -> bf16 round-to-nearest-even
__device__ __forceinline__ u16 f2bf(float f) {
    uint32 u = __float_as_uint(f);
    u += 0x7fffu + ((u >> 16) & 1u);
    return (u16)(u >> 16);
}

// ---------------------------------------------------------------------------
// 1) prep_all: ONE launch fusing
//    blocks [0,512):     bilinear upsample + transpose-cast ctx -> ctx_t bf16
//    blocks [512,1024):  transpose-cast sr -> sr_t bf16
//    blocks [1024,1920): weight prep (Wq*log2e|Wk|Wv -> w_bf; Wp -> wt)
//    blocks [1920,5073): zero att_t + acc + lacc
// ---------------------------------------------------------------------------
__global__ __launch_bounds__(256) void prep_all(const float* __restrict__ ctx,
                                                const float* __restrict__ sr,
                                                const float* __restrict__ Wq,
                                                const float* __restrict__ Wk,
                                                const float* __restrict__ Wv,
                                                const float* __restrict__ Wp,
                                                u16* __restrict__ ctx_t,
                                                u16* __restrict__ sr_t,
                                                u16* __restrict__ wbf,
                                                u16* __restrict__ wt,
                                                uint4* __restrict__ att_z,
                                                uint4* __restrict__ acc_z) {
    __shared__ float smem[2 * 32 * 130];   // 33.3 KB, reused by both transpose paths
    int blk = blockIdx.x;
    int tid = threadIdx.x;

    if (blk < 512) {
        // ---- upsample + transpose-cast ----
        float (*ls)[32][130] = (float(*)[32][130])smem;
        int y = blk & 63;
        int cch = (blk >> 6) & 1;
        int b = blk >> 7;
        float sy = y * 0.5f - 0.25f;
        int y0 = (int)floorf(sy);
        float wy = sy - (float)y0;
        int y0c = y0 < 0 ? 0 : y0;
        int y1c = (y0 + 1 > HC - 1) ? HC - 1 : y0 + 1;
#pragma unroll
        for (int t = 0; t < 4; t++) {
            int CI = t * 256 + tid;
            int cc = CI >> 3, xq = CI & 7;
            const float* s = ctx + (size_t)(b * CCH + cch * 128 + cc) * (HC * WC);
            float4 v0 = *(const float4*)(s + y0c * WC + xq * 4);
            float4 v1 = *(const float4*)(s + y1c * WC + xq * 4);
            ls[0][xq * 4 + 0][cc] = v0.x; ls[0][xq * 4 + 1][cc] = v0.y;
            ls[0][xq * 4 + 2][cc] = v0.z; ls[0][xq * 4 + 3][cc] = v0.w;
            ls[1][xq * 4 + 0][cc] = v1.x; ls[1][xq * 4 + 1][cc] = v1.y;
            ls[1][xq * 4 + 2][cc] = v1.z; ls[1][xq * 4 + 3][cc] = v1.w;
        }
        __syncthreads();
        int occ = tid & 127, xh = tid >> 7;
        u16* ob = ctx_t + ((size_t)b * NN + (size_t)y * 64) * CCH + cch * 128 + occ;
        float wy1 = 1.f - wy;
#pragma unroll
        for (int xi = 0; xi < 32; xi++) {
            int x = xi * 2 + xh;
            float sx = x * 0.5f - 0.25f;
            int x0 = (int)floorf(sx);
            float wx = sx - (float)x0;
            int x0c = x0 < 0 ? 0 : x0;
            int x1c = (x0 + 1 > WC - 1) ? WC - 1 : x0 + 1;
            float v00 = ls[0][x0c][occ], v01 = ls[0][x1c][occ];
            float v10 = ls[1][x0c][occ], v11 = ls[1][x1c][occ];
            float val = wy1 * ((1.f - wx) * v00 + wx * v01)
                      + wy  * ((1.f - wx) * v10 + wx * v11);
            ob[(size_t)x * CCH] = f2bf(val);
        }
    } else if (blk < 1024) {
        // ---- transpose-cast sr f32 [b][C][NN] -> sr_t bf16 [b][NN][C] ----
        float* ls = smem;   // 64*65
        int idx = blk - 512;
        int n0 = (idx & 63) * 64;
        int ci0 = ((idx >> 6) & 1) * 64;
        int b = idx >> 7;
        const float* inb = sr + ((size_t)b * C + ci0) * NN + n0;
#pragma unroll
        for (int L = 0; L < 4; L++) {
            int fc = tid + L * 256;
            int nc = fc & 15, ci = fc >> 4;
            float4 v = *(const float4*)(inb + (size_t)ci * NN + nc * 4);
            float* d = &ls[ci * 65 + nc * 4];
            d[0] = v.x; d[1] = v.y; d[2] = v.z; d[3] = v.w;
        }
        __syncthreads();
        u16* ob = sr_t + ((size_t)b * NN + n0) * C + ci0;
#pragma unroll
        for (int j = 0; j < 16; j++) {
            int o = tid + j * 256;
            int ci = o & 63, n = o >> 6;
            ob[(size_t)n * C + ci] = f2bf(ls[ci * 65 + n]);
        }
    } else if (blk < 1920) {
        int i = (blk - 1024) * 256 + tid;   // 0..229375
        if (i < 81920) {
            float v;
            if (i < 16384) v = Wq[i] * LOG2E;
            else if (i < 49152) v = Wk[i - 16384];
            else v = Wv[i - 49152];
            wbf[i] = f2bf(v);
        } else {
            int idx = i - 81920;
            int ciin = idx & 31;
            int co = (idx >> 5) & 127;
            int cb = (idx >> 12) & 3;
            int pos = idx >> 14;
            int ky = pos / 3, kx = pos - ky * 3;
            int ci = cb * 32 + ciin;
            wt[idx] = f2bf(Wp[((size_t)(co * C + ci) * 3 + ky) * 3 + kx]);
        }
    } else {
        int i = (blk - 1920) * 256 + tid;   // 0..807167
        if (i < 278784) att_z[i] = make_uint4(0, 0, 0, 0);
        else acc_z[i - 278784] = make_uint4(0, 0, 0, 0);
    }
}

// ---------------------------------------------------------------------------
// 2) Fused projection GEMM (q/k/v by blockIdx.z), LDS-staged. (r6, proven)
// ---------------------------------------------------------------------------
__global__ __launch_bounds__(256) void proj_all(const u16* __restrict__ sr_t,
                                                const u16* __restrict__ ctx_t,
                                                const u16* __restrict__ wbf,
                                                const float* __restrict__ bq,
                                                const float* __restrict__ bk,
                                                const float* __restrict__ bv,
                                                u16* __restrict__ q_t,
                                                u16* __restrict__ k_t,
                                                u16* __restrict__ v_bf) {
    __shared__ u16 xs[128 * 64];
    __shared__ u16 wsm[128 * 64];
    int z = blockIdx.z;
    int b = blockIdx.y;
    int n0 = blockIdx.x * 128;
    int Cin = (z == 0) ? C : CCH;
    const u16* xb = (z == 0 ? sr_t : ctx_t) + (size_t)b * NN * Cin;
    const u16* wb = wbf + (z == 0 ? 0 : (z == 1 ? 16384 : 49152));
    const float* bias = (z == 0) ? bq : (z == 1 ? bk : bv);
    float bsc = (z == 0) ? LOG2E : 1.0f;
    bool vmode = (z == 2);

    int tid = threadIdx.x;
    int w = tid >> 6, lane = tid & 63, l31 = lane & 31, half = lane >> 5;
    int xh = w >> 1, wh = w & 1;

    f32x16 acc[2][2];
#pragma unroll
    for (int xt = 0; xt < 2; xt++)
#pragma unroll
        for (int wt2 = 0; wt2 < 2; wt2++)
#pragma unroll
            for (int i = 0; i < 16; i++) acc[xt][wt2][i] = 0.f;

    int nchunks = Cin >> 6;
    for (int c0i = 0; c0i < nchunks; c0i++) {
        int c0 = c0i * 64;
        __syncthreads();
#pragma unroll
        for (int t = 0; t < 4; t++) {
            int CI = t * 256 + tid;
            int row = CI >> 3, sl = CI & 7;
            int lc = sl ^ (row & 7);
            __builtin_amdgcn_global_load_lds(
                (const __attribute__((address_space(1))) void*)(xb + (size_t)(n0 + row) * Cin + c0 + lc * 8),
                (__attribute__((address_space(3))) void*)&xs[(size_t)CI * 8], 16, 0, 0);
        }
#pragma unroll
        for (int t = 0; t < 4; t++) {
            int CI = t * 256 + tid;
            int co = CI >> 3, sl = CI & 7;
            int lc = sl ^ (co & 7);
            __builtin_amdgcn_global_load_lds(
                (const __attribute__((address_space(1))) void*)(wb + (size_t)co * Cin + c0 + lc * 8),
                (__attribute__((address_space(3))) void*)&wsm[(size_t)CI * 8], 16, 0, 0);
        }
        __syncthreads();
#pragma unroll
        for (int kg = 0; kg < 4; kg++) {
            int pc = ((kg * 2 + half) ^ (l31 & 7)) * 8;
            s16x8 xf[2], wf2[2];
#pragma unroll
            for (int xt = 0; xt < 2; xt++)
                xf[xt] = *(const s16x8*)&xs[(xh * 64 + xt * 32 + l31) * 64 + pc];
#pragma unroll
            for (int wt2 = 0; wt2 < 2; wt2++)
                wf2[wt2] = *(const s16x8*)&wsm[(wh * 64 + wt2 * 32 + l31) * 64 + pc];
#pragma unroll
            for (int xt = 0; xt < 2; xt++)
#pragma unroll
                for (int wt2 = 0; wt2 < 2; wt2++) {
                    if (vmode)
                        acc[xt][wt2] = __builtin_amdgcn_mfma_f32_32x32x16_bf16(wf2[wt2], xf[xt], acc[xt][wt2], 0, 0, 0);
                    else
                        acc[xt][wt2] = __builtin_amdgcn_mfma_f32_32x32x16_bf16(xf[xt], wf2[wt2], acc[xt][wt2], 0, 0, 0);
                }
        }
    }

    if (!vmode) {
        u16* ot = (z == 0 ? q_t : k_t) + (size_t)b * NN * C;
        float bv2[2];
#pragma unroll
        for (int wt2 = 0; wt2 < 2; wt2++) bv2[wt2] = bias[wh * 64 + wt2 * 32 + l31] * bsc;
#pragma unroll
        for (int xt = 0; xt < 2; xt++)
#pragma unroll
            for (int r = 0; r < 16; r++) {
                int n = n0 + xh * 64 + xt * 32 + (r & 3) + 8 * (r >> 2) + 4 * half;
#pragma unroll
                for (int wt2 = 0; wt2 < 2; wt2++)
                    ot[(size_t)n * C + wh * 64 + wt2 * 32 + l31] = f2bf(acc[xt][wt2][r] + bv2[wt2]);
            }
    } else {
        u16* ov = v_bf + (size_t)b * C * NN;
#pragma unroll
        for (int wt2 = 0; wt2 < 2; wt2++)
#pragma unroll
            for (int r = 0; r < 16; r++) {
                int co = wh * 64 + wt2 * 32 + (r & 3) + 8 * (r >> 2) + 4 * half;
                float bvv = bias[co];
#pragma unroll
                for (int xt = 0; xt < 2; xt++) {
                    int n = n0 + xh * 64 + xt * 32 + l31;
                    ov[(size_t)co * NN + n] = f2bf(acc[xt][wt2][r] + bvv);
                }
            }
    }
}

// ---------------------------------------------------------------------------
// 3) Flash attention v8: r6's proven staged 2-barrier skeleton (1 q-tile/wave,
//    32q, oacc=64 AGPR -- NO spills) + register P-transpose via __shfl_xor(32)
//    (no ps LDS buffer: kills the ds_write->ds_read serial chain and its bank
//    conflicts; LDS 32 KB) + exp2 (Q pre-scaled by log2e).
//    Block 256 thr = 4 waves x 32q = 128 q. Split-K x8. Grid 1024.
// ---------------------------------------------------------------------------
__global__ __launch_bounds__(256) void flash_mfma(const u16* __restrict__ qt_p,
                                                  const u16* __restrict__ kt_p,
                                                  const u16* __restrict__ vt_p,
                                                  float* __restrict__ acc,
                                                  float* __restrict__ lacc) {
    __shared__ u16 ks[64 * 128];     // [key][ch] chunk-XOR16 swizzled, 16 KB
    __shared__ u16 vs[128 * 64];     // [ch][key] chunk-XOR8 swizzled,  16 KB

    int ib = blockIdx.x;
    int b = (ib & 7) >> 1;                       // batch -> XCD pair
    int rest = ((ib >> 3) << 1) | (ib & 1);      // 0..255
    int qtile = rest >> 3;                       // 0..31
    int split = rest & 7;
    int n0 = qtile * 128;
    int tid = threadIdx.x;
    int w = tid >> 6, lane = tid & 63, l31 = lane & 31, half = lane >> 5;

    const u16* qtb = qt_p + (size_t)b * NN * C;
    const u16* ktb = kt_p + (size_t)b * NN * C;
    const u16* vtb = vt_p + (size_t)b * C * NN;

    auto stageK = [&](int m0) {
#pragma unroll
        for (int t = 0; t < 4; t++) {
            int CI = (w * 4 + t) * 64 + lane;
            int r = CI >> 4;
            int lc = (CI & 15) ^ (r & 15);
            __builtin_amdgcn_global_load_lds(
                (const __attribute__((address_space(1))) void*)(ktb + (size_t)(m0 + r) * C + lc * 8),
                (__attribute__((address_space(3))) void*)&ks[(w * 4 + t) * 512], 16, 0, 0);
        }
    };
    auto stageV = [&](int m0) {
#pragma unroll
        for (int t = 0; t < 4; t++) {
            int CI = (w * 4 + t) * 64 + lane;
            int c = CI >> 3;
            int lc = (CI & 7) ^ (c & 7);
            __builtin_amdgcn_global_load_lds(
                (const __attribute__((address_space(1))) void*)(vtb + (size_t)c * NN + m0 + lc * 8),
                (__attribute__((address_space(3))) void*)&vs[(w * 4 + t) * 512], 16, 0, 0);
        }
    };

    // Q B-fragments in registers (reused all iterations)
    int qrow = n0 + w * 32 + l31;
    s16x8 qf[8];
#pragma unroll
    for (int kg = 0; kg < 8; kg++)
        qf[kg] = *(const s16x8*)(qtb + (size_t)qrow * C + kg * 16 + half * 8);

    int m_base = split * 512;
    stageK(m_base);
    __syncthreads();

    f32x16 oacc[4];
#pragma unroll
    for (int mt = 0; mt < 4; mt++)
#pragma unroll
        for (int i = 0; i < 16; i++) oacc[mt][i] = 0.f;
    float lsum = 0.f;

    for (int it = 0; it < 8; it++) {
        int m0 = m_base + it * 64;
        stageV(m0);                               // async, drains at barrier 1

        // ---- S^T = K·Q : rows m (2 tiles of 32), cols q (32) ----
        f32x16 st[2];
#pragma unroll
        for (int kmt = 0; kmt < 2; kmt++)
#pragma unroll
            for (int i = 0; i < 16; i++) st[kmt][i] = 0.f;
#pragma unroll
        for (int kg = 0; kg < 8; kg++) {
            int pc = ((kg * 2 + half) ^ (l31 & 15)) * 8;
#pragma unroll
            for (int kmt = 0; kmt < 2; kmt++) {
                s16x8 kf = *(const s16x8*)&ks[(kmt * 32 + l31) * 128 + pc];
                st[kmt] = __builtin_amdgcn_mfma_f32_32x32x16_bf16(kf, qf[kg], st[kmt], 0, 0, 0);
            }
        }
        __syncthreads();                          // V staged; all waves done with ks
        if (it < 7) stageK(m0 + 64);              // async, drains at barrier 2

        // ---- exp2 + register P-transpose (shfl_xor 32) + PV ----
#pragma unroll
        for (int kmt = 0; kmt < 2; kmt++) {
            float e[16];
            float ls = 0.f;
#pragma unroll
            for (int r = 0; r < 16; r++) { e[r] = exp2f(st[kmt][r]); ls += e[r]; }
            lsum += ls;
            uint32 A[4], B4[4];
#pragma unroll
            for (int g = 0; g < 4; g++) {
                A[g]  = __builtin_amdgcn_perm(__float_as_uint(e[4 * g + 1]), __float_as_uint(e[4 * g + 0]), 0x07060302u);
                B4[g] = __builtin_amdgcn_perm(__float_as_uint(e[4 * g + 3]), __float_as_uint(e[4 * g + 2]), 0x07060302u);
            }
#pragma unroll
            for (int s = 0; s < 2; s++) {
                uint32 sendA = half ? A[2 * s] : A[2 * s + 1];
                uint32 sendB = half ? B4[2 * s] : B4[2 * s + 1];
                uint32 rA = __shfl_xor(sendA, 32);
                uint32 rB = __shfl_xor(sendB, 32);
                uint32 oA = half ? A[2 * s + 1] : A[2 * s];
                uint32 oB = half ? B4[2 * s + 1] : B4[2 * s];
                union { uint32 u[4]; s16x8 v; } pu;
                pu.u[0] = half ? rA : oA;
                pu.u[1] = half ? rB : oB;
                pu.u[2] = half ? oA : rA;
                pu.u[3] = half ? oB : rB;
                s16x8 pf = pu.v;
                int kgp = kmt * 2 + s;
                int pcv = ((kgp * 2 + half) ^ (l31 & 7)) * 8;
#pragma unroll
                for (int mt = 0; mt < 4; mt++) {
                    s16x8 vf = *(const s16x8*)&vs[(mt * 32 + l31) * 64 + pcv];
                    oacc[mt] = __builtin_amdgcn_mfma_f32_32x32x16_bf16(vf, pf, oacc[mt], 0, 0, 0);
                }
            }
        }
        __syncthreads();                          // K(it+1) staged; vs free
    }

    // ---- epilogue: lsum across halves; coalesced atomic adds ----
    float lt = lsum + __shfl_xor(lsum, 32);
    if (half == 0) atomicAdd(&lacc[(size_t)b * NN + qrow], lt);
    float* ab = acc + (size_t)b * C * NN;
#pragma unroll
    for (int mt = 0; mt < 4; mt++)
#pragma unroll
        for (int r = 0; r < 16; r++) {
            int c = mt * 32 + (r & 3) + 8 * (r >> 2) + 4 * half;
            atomicAdd(&ab[(size_t)c * NN + n0 + w * 32 + l31], oacc[mt][r]);
        }
}

// ---------------------------------------------------------------------------
// 4) Combine: att_t[b][y+1][x+1][c] = bf16( acc[b][c][n] / lacc[b][n] )
// ---------------------------------------------------------------------------
__global__ __launch_bounds__(256) void flash_combine(const float* __restrict__ acc,
                                                     const float* __restrict__ lacc,
                                                     u16* __restrict__ att_t) {
    __shared__ u16 ts[128 * 66];
    __shared__ float linv[64];
    int b = blockIdx.y;
    int nt = blockIdx.x;
    int n0 = nt * 64;
    int tid = threadIdx.x;
    if (tid < 64) linv[tid] = 1.0f / lacc[(size_t)b * NN + n0 + tid];
    __syncthreads();
    const float* ab = acc + (size_t)b * C * NN + n0;
#pragma unroll
    for (int j = 0; j < 32; j++) {
        int e = tid + j * 256;
        int n = e & 63, c = e >> 6;
        ts[c * 66 + n] = f2bf(ab[(size_t)c * NN + n] * linv[n]);
    }
    __syncthreads();
    u16* ob = att_t + ((size_t)b * PP * PP + (size_t)(nt + 1) * PP + 1) * C;
#pragma unroll
    for (int j = 0; j < 32; j++) {
        int o = tid + j * 256;
        int c = o & 127, n = o >> 7;
        ob[(size_t)n * C + c] = ts[c * 66 + n];
    }
}

// ---------------------------------------------------------------------------
// 5) Implicit-GEMM MFMA conv3x3 + residual (r7: px-split grid 512, hoisted
//    weight frags).
// ---------------------------------------------------------------------------
__global__ __launch_bounds__(256) void conv3x3_mfma(const u16* __restrict__ att_t,
                                                    const u16* __restrict__ wt,
                                                    const float* __restrict__ bp,
                                                    const float* __restrict__ sr,
                                                    const float* __restrict__ gamma,
                                                    float* __restrict__ out) {
    __shared__ u16 in_s[2][4 * 102 * 8];
    int ib = blockIdx.x;
    int b = (ib & 7) >> 1;
    int rr = ((ib >> 3) << 1) | (ib & 1);
    int y = rr >> 1;
    int x0 = (rr & 1) * 32;
    int tid = threadIdx.x;
    int w = tid >> 6, lane = tid & 63, l = tid & 15, quad = (tid >> 4) & 3;
    const u16* ab = att_t + (size_t)b * (PP * PP * C);

    auto stage = [&](int cib, int bufi) {
        u16* base = &in_s[bufi][w * 102 * 8];
        const u16* gsrc = ab + cib * 32 + w * 8;
#pragma unroll
        for (int t = 0; t < 2; t++) {
            int idx = t * 64 + lane;
            int r = idx / 34, xp = idx - r * 34;
            if (t == 0 || lane < 38)
                __builtin_amdgcn_global_load_lds(
                    (const __attribute__((address_space(1))) void*)(gsrc + (size_t)((y + r) * PP + x0 + xp) * C),
                    (__attribute__((address_space(3))) void*)(base + (size_t)t * 64 * 8), 16, 0, 0);
        }
    };

    f32x4 accr[2][2];
#pragma unroll
    for (int cf = 0; cf < 2; cf++)
#pragma unroll
        for (int nf = 0; nf < 2; nf++) accr[cf][nf] = (f32x4){0.f, 0.f, 0.f, 0.f};
    int cow = w * 32;

    stage(0, 0);
    __syncthreads();
#pragma unroll
    for (int cib = 0; cib < 4; cib++) {
        if (cib < 3) stage(cib + 1, (cib + 1) & 1);
        s16x8 wf[9][2];
#pragma unroll
        for (int pos = 0; pos < 9; pos++)
#pragma unroll
            for (int cf = 0; cf < 2; cf++)
                wf[pos][cf] = *(const s16x8*)&wt[((size_t)(pos * 4 + cib) * C + cow + cf * 16 + l) * 32 + quad * 8];
        const u16* bufc = &in_s[cib & 1][0];
#pragma unroll
        for (int ky = 0; ky < 3; ky++)
#pragma unroll
            for (int kx = 0; kx < 3; kx++) {
                int pos = ky * 3 + kx;
#pragma unroll
                for (int nf = 0; nf < 2; nf++) {
                    s16x8 inf = *(const s16x8*)&bufc[(quad * 102 + ky * 34 + nf * 16 + l + kx) * 8];
                    accr[0][nf] = __builtin_amdgcn_mfma_f32_16x16x32_bf16(wf[pos][0], inf, accr[0][nf], 0, 0, 0);
                    accr[1][nf] = __builtin_amdgcn_mfma_f32_16x16x32_bf16(wf[pos][1], inf, accr[1][nf], 0, 0, 0);
                }
            }
        __syncthreads();
    }

    float g = gamma[0];
    float* ob = out + (size_t)b * C * NN;
    const float* sb = sr + (size_t)b * C * NN;
#pragma unroll
    for (int cf = 0; cf < 2; cf++)
#pragma unroll
        for (int r = 0; r < 4; r++) {
            int co = cow + cf * 16 + quad * 4 + r;
            float bias = bp[co];
#pragma unroll
            for (int nf = 0; nf < 2; nf++) {
                size_t oo = (size_t)co * NN + y * 64 + x0 + nf * 16 + l;
                ob[oo] = sb[oo] + g * (accr[cf][nf][r] + bias);
            }
        }
}

// ---------------------------------------------------------------------------
extern "C" void kernel_launch(void* const* d_in, const int* in_sizes, int n_in,
                              void* d_out, int out_size, void* d_ws, size_t ws_size,
                              hipStream_t stream) {
    const float* sr    = (const float*)d_in[0];
    const float* ctx   = (const float*)d_in[1];
    const float* Wq    = (const float*)d_in[2];
    const float* bq    = (const float*)d_in[3];
    const float* Wk    = (const float*)d_in[4];
    const float* bk    = (const float*)d_in[5];
    const float* Wv    = (const float*)d_in[6];
    const float* bv    = (const float*)d_in[7];
    const float* Wp    = (const float*)d_in[8];
    const float* bp    = (const float*)d_in[9];
    const float* gamma = (const float*)d_in[10];
    float* out = (float*)d_out;

    char* wsb = (char*)d_ws;
    u16*   att_t  = (u16*)wsb;                         // @0, 4,460,544 B
    float* acc    = (float*)(wsb + (5u << 20));        // 8 MB
    float* lacc   = acc + (size_t)NB * C * NN;         // 64 KB
    u16*   ctx_t  = (u16*)(wsb + (14u << 20));         // 8 MB
    u16*   sr_t   = (u16*)(wsb + (22u << 20));         // 4 MB
    u16*   q_t    = (u16*)(wsb + (26u << 20));         // 4 MB
    u16*   k_t    = (u16*)(wsb + (30u << 20));         // 4 MB
    u16*   v_bf   = (u16*)(wsb + (34u << 20));         // 4 MB
    u16*   wt     = (u16*)(wsb + (38u << 20));         // 294,912 B
    u16*   w_bf   = (u16*)(wsb + (38u << 20) + (512u << 10));

    prep_all<<<dim3(5073), 256, 0, stream>>>(ctx, sr, Wq, Wk, Wv, Wp,
                                             ctx_t, sr_t, w_bf, wt,
                                             (uint4*)att_t, (uint4*)acc);
    proj_all<<<dim3(32, NB, 3), 256, 0, stream>>>(sr_t, ctx_t, w_bf, bq, bk, bv,
                                                  q_t, k_t, v_bf);
    flash_mfma<<<dim3(1024), 256, 0, stream>>>(q_t, k_t, v_bf, acc, lacc);
    flash_combine<<<dim3(64, NB), 256, 0, stream>>>(acc, lacc, att_t);
    conv3x3_mfma<<<dim3(512), 256, 0, stream>>>(att_t, wt, bp, sr, gamma, out);
}

// Round 9
// 168.378 us; speedup vs baseline: 1.5889x; 1.2369x over previous
//
#include <hip/hip_runtime.h>
#include <math.h>

// Problem constants
#define NB 4      // batch
#define C  128    // channels (q/k/v/out)
#define CCH 256   // context channels
#define HH 64
#define WW 64
#define NN 4096   // HH*WW
#define HC 32
#define WC 32
#define PP 66     // padded spatial dim for conv input (64 + 2 halo)
#define LOG2E 1.44269504088896f
#define NSPLIT 4  // flash split-K factor

typedef unsigned short u16;
typedef unsigned int uint32;
typedef short s16x8 __attribute__((ext_vector_type(8)));    // 8 bf16 = MFMA A/B frag
typedef float f32x4 __attribute__((ext_vector_type(4)));    // 16x16 MFMA C/D frag
typedef float f32x16 __attribute__((ext_vector_type(16)));  // 32x32 MFMA C/D frag

// fp32 -> bf16 round-to-nearest-even
__device__ __forceinline__ u16 f2bf(float f) {
    uint32 u = __float_as_uint(f);
    u += 0x7fffu + ((u >> 16) & 1u);
    return (u16)(u >> 16);
}
__device__ __forceinline__ float bf2f(u16 h) {
    return __uint_as_float((uint32)h << 16);
}

// ---------------------------------------------------------------------------
// 1) prep_all: ONE launch fusing
//    blocks [0,512):     bilinear upsample + transpose-cast ctx -> ctx_t bf16
//    blocks [512,1024):  transpose-cast sr -> sr_t bf16
//    blocks [1024,1920): weight prep (Wq*log2e|Wk|Wv -> w_bf; Wp -> wt)
//    blocks [1920,3009): zero att_t border buffer
// ---------------------------------------------------------------------------
__global__ __launch_bounds__(256) void prep_all(const float* __restrict__ ctx,
                                                const float* __restrict__ sr,
                                                const float* __restrict__ Wq,
                                                const float* __restrict__ Wk,
                                                const float* __restrict__ Wv,
                                                const float* __restrict__ Wp,
                                                u16* __restrict__ ctx_t,
                                                u16* __restrict__ sr_t,
                                                u16* __restrict__ wbf,
                                                u16* __restrict__ wt,
                                                uint4* __restrict__ att_z) {
    __shared__ float smem[2 * 32 * 130];   // 33.3 KB, reused by both transpose paths
    int blk = blockIdx.x;
    int tid = threadIdx.x;

    if (blk < 512) {
        // ---- upsample + transpose-cast ----
        float (*ls)[32][130] = (float(*)[32][130])smem;
        int y = blk & 63;
        int cch = (blk >> 6) & 1;
        int b = blk >> 7;
        float sy = y * 0.5f - 0.25f;
        int y0 = (int)floorf(sy);
        float wy = sy - (float)y0;
        int y0c = y0 < 0 ? 0 : y0;
        int y1c = (y0 + 1 > HC - 1) ? HC - 1 : y0 + 1;
#pragma unroll
        for (int t = 0; t < 4; t++) {
            int CI = t * 256 + tid;
            int cc = CI >> 3, xq = CI & 7;
            const float* s = ctx + (size_t)(b * CCH + cch * 128 + cc) * (HC * WC);
            float4 v0 = *(const float4*)(s + y0c * WC + xq * 4);
            float4 v1 = *(const float4*)(s + y1c * WC + xq * 4);
            ls[0][xq * 4 + 0][cc] = v0.x; ls[0][xq * 4 + 1][cc] = v0.y;
            ls[0][xq * 4 + 2][cc] = v0.z; ls[0][xq * 4 + 3][cc] = v0.w;
            ls[1][xq * 4 + 0][cc] = v1.x; ls[1][xq * 4 + 1][cc] = v1.y;
            ls[1][xq * 4 + 2][cc] = v1.z; ls[1][xq * 4 + 3][cc] = v1.w;
        }
        __syncthreads();
        int occ = tid & 127, xh = tid >> 7;
        u16* ob = ctx_t + ((size_t)b * NN + (size_t)y * 64) * CCH + cch * 128 + occ;
        float wy1 = 1.f - wy;
#pragma unroll
        for (int xi = 0; xi < 32; xi++) {
            int x = xi * 2 + xh;
            float sx = x * 0.5f - 0.25f;
            int x0 = (int)floorf(sx);
            float wx = sx - (float)x0;
            int x0c = x0 < 0 ? 0 : x0;
            int x1c = (x0 + 1 > WC - 1) ? WC - 1 : x0 + 1;
            float v00 = ls[0][x0c][occ], v01 = ls[0][x1c][occ];
            float v10 = ls[1][x0c][occ], v11 = ls[1][x1c][occ];
            float val = wy1 * ((1.f - wx) * v00 + wx * v01)
                      + wy  * ((1.f - wx) * v10 + wx * v11);
            ob[(size_t)x * CCH] = f2bf(val);
        }
    } else if (blk < 1024) {
        // ---- transpose-cast sr f32 [b][C][NN] -> sr_t bf16 [b][NN][C] ----
        float* ls = smem;   // 64*65
        int idx = blk - 512;
        int n0 = (idx & 63) * 64;
        int ci0 = ((idx >> 6) & 1) * 64;
        int b = idx >> 7;
        const float* inb = sr + ((size_t)b * C + ci0) * NN + n0;
#pragma unroll
        for (int L = 0; L < 4; L++) {
            int fc = tid + L * 256;
            int nc = fc & 15, ci = fc >> 4;
            float4 v = *(const float4*)(inb + (size_t)ci * NN + nc * 4);
            float* d = &ls[ci * 65 + nc * 4];
            d[0] = v.x; d[1] = v.y; d[2] = v.z; d[3] = v.w;
        }
        __syncthreads();
        u16* ob = sr_t + ((size_t)b * NN + n0) * C + ci0;
#pragma unroll
        for (int j = 0; j < 16; j++) {
            int o = tid + j * 256;
            int ci = o & 63, n = o >> 6;
            ob[(size_t)n * C + ci] = f2bf(ls[ci * 65 + n]);
        }
    } else if (blk < 1920) {
        int i = (blk - 1024) * 256 + tid;   // 0..229375
        if (i < 81920) {
            float v;
            if (i < 16384) v = Wq[i] * LOG2E;
            else if (i < 49152) v = Wk[i - 16384];
            else v = Wv[i - 49152];
            wbf[i] = f2bf(v);
        } else {
            int idx = i - 81920;
            int ciin = idx & 31;
            int co = (idx >> 5) & 127;
            int cb = (idx >> 12) & 3;
            int pos = idx >> 14;
            int ky = pos / 3, kx = pos - ky * 3;
            int ci = cb * 32 + ciin;
            wt[idx] = f2bf(Wp[((size_t)(co * C + ci) * 3 + ky) * 3 + kx]);
        }
    } else {
        int i = (blk - 1920) * 256 + tid;   // 0..278783
        if (i < 278784) att_z[i] = make_uint4(0, 0, 0, 0);
    }
}

// ---------------------------------------------------------------------------
// 2) Fused projection GEMM (q/k/v by blockIdx.z), LDS-staged. (r6, proven)
// ---------------------------------------------------------------------------
__global__ __launch_bounds__(256) void proj_all(const u16* __restrict__ sr_t,
                                                const u16* __restrict__ ctx_t,
                                                const u16* __restrict__ wbf,
                                                const float* __restrict__ bq,
                                                const float* __restrict__ bk,
                                                const float* __restrict__ bv,
                                                u16* __restrict__ q_t,
                                                u16* __restrict__ k_t,
                                                u16* __restrict__ v_bf) {
    __shared__ u16 xs[128 * 64];
    __shared__ u16 wsm[128 * 64];
    int z = blockIdx.z;
    int b = blockIdx.y;
    int n0 = blockIdx.x * 128;
    int Cin = (z == 0) ? C : CCH;
    const u16* xb = (z == 0 ? sr_t : ctx_t) + (size_t)b * NN * Cin;
    const u16* wb = wbf + (z == 0 ? 0 : (z == 1 ? 16384 : 49152));
    const float* bias = (z == 0) ? bq : (z == 1 ? bk : bv);
    float bsc = (z == 0) ? LOG2E : 1.0f;
    bool vmode = (z == 2);

    int tid = threadIdx.x;
    int w = tid >> 6, lane = tid & 63, l31 = lane & 31, half = lane >> 5;
    int xh = w >> 1, wh = w & 1;

    f32x16 acc[2][2];
#pragma unroll
    for (int xt = 0; xt < 2; xt++)
#pragma unroll
        for (int wt2 = 0; wt2 < 2; wt2++)
#pragma unroll
            for (int i = 0; i < 16; i++) acc[xt][wt2][i] = 0.f;

    int nchunks = Cin >> 6;
    for (int c0i = 0; c0i < nchunks; c0i++) {
        int c0 = c0i * 64;
        __syncthreads();
#pragma unroll
        for (int t = 0; t < 4; t++) {
            int CI = t * 256 + tid;
            int row = CI >> 3, sl = CI & 7;
            int lc = sl ^ (row & 7);
            __builtin_amdgcn_global_load_lds(
                (const __attribute__((address_space(1))) void*)(xb + (size_t)(n0 + row) * Cin + c0 + lc * 8),
                (__attribute__((address_space(3))) void*)&xs[(size_t)CI * 8], 16, 0, 0);
        }
#pragma unroll
        for (int t = 0; t < 4; t++) {
            int CI = t * 256 + tid;
            int co = CI >> 3, sl = CI & 7;
            int lc = sl ^ (co & 7);
            __builtin_amdgcn_global_load_lds(
                (const __attribute__((address_space(1))) void*)(wb + (size_t)co * Cin + c0 + lc * 8),
                (__attribute__((address_space(3))) void*)&wsm[(size_t)CI * 8], 16, 0, 0);
        }
        __syncthreads();
#pragma unroll
        for (int kg = 0; kg < 4; kg++) {
            int pc = ((kg * 2 + half) ^ (l31 & 7)) * 8;
            s16x8 xf[2], wf2[2];
#pragma unroll
            for (int xt = 0; xt < 2; xt++)
                xf[xt] = *(const s16x8*)&xs[(xh * 64 + xt * 32 + l31) * 64 + pc];
#pragma unroll
            for (int wt2 = 0; wt2 < 2; wt2++)
                wf2[wt2] = *(const s16x8*)&wsm[(wh * 64 + wt2 * 32 + l31) * 64 + pc];
#pragma unroll
            for (int xt = 0; xt < 2; xt++)
#pragma unroll
                for (int wt2 = 0; wt2 < 2; wt2++) {
                    if (vmode)
                        acc[xt][wt2] = __builtin_amdgcn_mfma_f32_32x32x16_bf16(wf2[wt2], xf[xt], acc[xt][wt2], 0, 0, 0);
                    else
                        acc[xt][wt2] = __builtin_amdgcn_mfma_f32_32x32x16_bf16(xf[xt], wf2[wt2], acc[xt][wt2], 0, 0, 0);
                }
        }
    }

    if (!vmode) {
        u16* ot = (z == 0 ? q_t : k_t) + (size_t)b * NN * C;
        float bv2[2];
#pragma unroll
        for (int wt2 = 0; wt2 < 2; wt2++) bv2[wt2] = bias[wh * 64 + wt2 * 32 + l31] * bsc;
#pragma unroll
        for (int xt = 0; xt < 2; xt++)
#pragma unroll
            for (int r = 0; r < 16; r++) {
                int n = n0 + xh * 64 + xt * 32 + (r & 3) + 8 * (r >> 2) + 4 * half;
#pragma unroll
                for (int wt2 = 0; wt2 < 2; wt2++)
                    ot[(size_t)n * C + wh * 64 + wt2 * 32 + l31] = f2bf(acc[xt][wt2][r] + bv2[wt2]);
            }
    } else {
        u16* ov = v_bf + (size_t)b * C * NN;
#pragma unroll
        for (int wt2 = 0; wt2 < 2; wt2++)
#pragma unroll
            for (int r = 0; r < 16; r++) {
                int co = wh * 64 + wt2 * 32 + (r & 3) + 8 * (r >> 2) + 4 * half;
                float bvv = bias[co];
#pragma unroll
                for (int xt = 0; xt < 2; xt++) {
                    int n = n0 + xh * 64 + xt * 32 + l31;
                    ov[(size_t)co * NN + n] = f2bf(acc[xt][wt2][r] + bvv);
                }
            }
    }
}

// ---------------------------------------------------------------------------
// 3) Flash attention v9: r8's inner loop (proven numerics) but NO ATOMICS —
//    each split writes its own bf16 partial buffer with plain coalesced
//    stores (atomics were the ~0.7 TB/s memory-side bottleneck, r8 PMC).
//    Split-K x4 (1024 keys/block, 16 iters). Grid 512 = 2 blocks/CU.
//    part[s][b][c][n] bf16; lpart[s][b][n] f32.
// ---------------------------------------------------------------------------
__global__ __launch_bounds__(256) void flash_mfma(const u16* __restrict__ qt_p,
                                                  const u16* __restrict__ kt_p,
                                                  const u16* __restrict__ vt_p,
                                                  u16* __restrict__ part,
                                                  float* __restrict__ lpart) {
    __shared__ u16 ks[64 * 128];     // [key][ch] chunk-XOR16 swizzled, 16 KB
    __shared__ u16 vs[128 * 64];     // [ch][key] chunk-XOR8 swizzled,  16 KB

    int ib = blockIdx.x;
    int b = (ib & 7) >> 1;                       // batch -> XCD pair
    int rest = ((ib >> 3) << 1) | (ib & 1);      // 0..127
    int qtile = rest >> 2;                       // 0..31
    int split = rest & 3;                        // 0..3
    int n0 = qtile * 128;
    int tid = threadIdx.x;
    int w = tid >> 6, lane = tid & 63, l31 = lane & 31, half = lane >> 5;

    const u16* qtb = qt_p + (size_t)b * NN * C;
    const u16* ktb = kt_p + (size_t)b * NN * C;
    const u16* vtb = vt_p + (size_t)b * C * NN;

    auto stageK = [&](int m0) {
#pragma unroll
        for (int t = 0; t < 4; t++) {
            int CI = (w * 4 + t) * 64 + lane;
            int r = CI >> 4;
            int lc = (CI & 15) ^ (r & 15);
            __builtin_amdgcn_global_load_lds(
                (const __attribute__((address_space(1))) void*)(ktb + (size_t)(m0 + r) * C + lc * 8),
                (__attribute__((address_space(3))) void*)&ks[(w * 4 + t) * 512], 16, 0, 0);
        }
    };
    auto stageV = [&](int m0) {
#pragma unroll
        for (int t = 0; t < 4; t++) {
            int CI = (w * 4 + t) * 64 + lane;
            int c = CI >> 3;
            int lc = (CI & 7) ^ (c & 7);
            __builtin_amdgcn_global_load_lds(
                (const __attribute__((address_space(1))) void*)(vtb + (size_t)c * NN + m0 + lc * 8),
                (__attribute__((address_space(3))) void*)&vs[(w * 4 + t) * 512], 16, 0, 0);
        }
    };

    // Q B-fragments in registers (reused all iterations)
    int qrow = n0 + w * 32 + l31;
    s16x8 qf[8];
#pragma unroll
    for (int kg = 0; kg < 8; kg++)
        qf[kg] = *(const s16x8*)(qtb + (size_t)qrow * C + kg * 16 + half * 8);

    int m_base = split * 1024;
    stageK(m_base);
    __syncthreads();

    f32x16 oacc[4];
#pragma unroll
    for (int mt = 0; mt < 4; mt++)
#pragma unroll
        for (int i = 0; i < 16; i++) oacc[mt][i] = 0.f;
    float lsum = 0.f;

    for (int it = 0; it < 16; it++) {
        int m0 = m_base + it * 64;
        stageV(m0);                               // async, drains at barrier 1

        // ---- S^T = K·Q : rows m (2 tiles of 32), cols q (32) ----
        f32x16 st[2];
#pragma unroll
        for (int kmt = 0; kmt < 2; kmt++)
#pragma unroll
            for (int i = 0; i < 16; i++) st[kmt][i] = 0.f;
#pragma unroll
        for (int kg = 0; kg < 8; kg++) {
            int pc = ((kg * 2 + half) ^ (l31 & 15)) * 8;
#pragma unroll
            for (int kmt = 0; kmt < 2; kmt++) {
                s16x8 kf = *(const s16x8*)&ks[(kmt * 32 + l31) * 128 + pc];
                st[kmt] = __builtin_amdgcn_mfma_f32_32x32x16_bf16(kf, qf[kg], st[kmt], 0, 0, 0);
            }
        }
        __syncthreads();                          // V staged; all waves done with ks
        if (it < 15) stageK(m0 + 64);             // async, drains at barrier 2

        // ---- exp2 + register P-transpose (shfl_xor 32) + PV ----
#pragma unroll
        for (int kmt = 0; kmt < 2; kmt++) {
            float e[16];
            float ls = 0.f;
#pragma unroll
            for (int r = 0; r < 16; r++) { e[r] = exp2f(st[kmt][r]); ls += e[r]; }
            lsum += ls;
            uint32 A[4], B4[4];
#pragma unroll
            for (int g = 0; g < 4; g++) {
                A[g]  = __builtin_amdgcn_perm(__float_as_uint(e[4 * g + 1]), __float_as_uint(e[4 * g + 0]), 0x07060302u);
                B4[g] = __builtin_amdgcn_perm(__float_as_uint(e[4 * g + 3]), __float_as_uint(e[4 * g + 2]), 0x07060302u);
            }
#pragma unroll
            for (int s = 0; s < 2; s++) {
                uint32 sendA = half ? A[2 * s] : A[2 * s + 1];
                uint32 sendB = half ? B4[2 * s] : B4[2 * s + 1];
                uint32 rA = __shfl_xor(sendA, 32);
                uint32 rB = __shfl_xor(sendB, 32);
                uint32 oA = half ? A[2 * s + 1] : A[2 * s];
                uint32 oB = half ? B4[2 * s + 1] : B4[2 * s];
                union { uint32 u[4]; s16x8 v; } pu;
                pu.u[0] = half ? rA : oA;
                pu.u[1] = half ? rB : oB;
                pu.u[2] = half ? oA : rA;
                pu.u[3] = half ? oB : rB;
                s16x8 pf = pu.v;
                int kgp = kmt * 2 + s;
                int pcv = ((kgp * 2 + half) ^ (l31 & 7)) * 8;
#pragma unroll
                for (int mt = 0; mt < 4; mt++) {
                    s16x8 vf = *(const s16x8*)&vs[(mt * 32 + l31) * 64 + pcv];
                    oacc[mt] = __builtin_amdgcn_mfma_f32_32x32x16_bf16(vf, pf, oacc[mt], 0, 0, 0);
                }
            }
        }
        __syncthreads();                          // K(it+1) staged; vs free
    }

    // ---- epilogue: plain coalesced stores of bf16 partials (NO atomics) ----
    float lt = lsum + __shfl_xor(lsum, 32);
    if (half == 0) lpart[(size_t)split * NB * NN + (size_t)b * NN + qrow] = lt;
    u16* pb = part + ((size_t)split * NB + b) * (size_t)C * NN;
#pragma unroll
    for (int mt = 0; mt < 4; mt++)
#pragma unroll
        for (int r = 0; r < 16; r++) {
            int c = mt * 32 + (r & 3) + 8 * (r >> 2) + 4 * half;
            pb[(size_t)c * NN + n0 + w * 32 + l31] = f2bf(oacc[mt][r]);
        }
}

// ---------------------------------------------------------------------------
// 4) Combine: att_t[b][y+1][x+1][c] = bf16( sum_s part[s][b][c][n] /
//                                           sum_s lpart[s][b][n] )
// ---------------------------------------------------------------------------
__global__ __launch_bounds__(256) void flash_combine(const u16* __restrict__ part,
                                                     const float* __restrict__ lpart,
                                                     u16* __restrict__ att_t) {
    __shared__ u16 ts[128 * 66];
    __shared__ float linv[64];
    int b = blockIdx.y;
    int nt = blockIdx.x;
    int n0 = nt * 64;
    int tid = threadIdx.x;
    if (tid < 64) {
        float s = 0.f;
#pragma unroll
        for (int sp = 0; sp < NSPLIT; sp++)
            s += lpart[(size_t)sp * NB * NN + (size_t)b * NN + n0 + tid];
        linv[tid] = 1.0f / s;
    }
    __syncthreads();
#pragma unroll
    for (int j = 0; j < 32; j++) {
        int e = tid + j * 256;
        int n = e & 63, c = e >> 6;
        float o = 0.f;
#pragma unroll
        for (int sp = 0; sp < NSPLIT; sp++)
            o += bf2f(part[((size_t)sp * NB + b) * (size_t)C * NN + (size_t)c * NN + n0 + n]);
        ts[c * 66 + n] = f2bf(o * linv[n]);
    }
    __syncthreads();
    u16* ob = att_t + ((size_t)b * PP * PP + (size_t)(nt + 1) * PP + 1) * C;
#pragma unroll
    for (int j = 0; j < 32; j++) {
        int o = tid + j * 256;
        int c = o & 127, n = o >> 7;
        ob[(size_t)n * C + c] = ts[c * 66 + n];
    }
}

// ---------------------------------------------------------------------------
// 5) Implicit-GEMM MFMA conv3x3 + residual (r7: px-split grid 512, hoisted
//    weight frags).
// ---------------------------------------------------------------------------
__global__ __launch_bounds__(256) void conv3x3_mfma(const u16* __restrict__ att_t,
                                                    const u16* __restrict__ wt,
                                                    const float* __restrict__ bp,
                                                    const float* __restrict__ sr,
                                                    const float* __restrict__ gamma,
                                                    float* __restrict__ out) {
    __shared__ u16 in_s[2][4 * 102 * 8];
    int ib = blockIdx.x;
    int b = (ib & 7) >> 1;
    int rr = ((ib >> 3) << 1) | (ib & 1);
    int y = rr >> 1;
    int x0 = (rr & 1) * 32;
    int tid = threadIdx.x;
    int w = tid >> 6, lane = tid & 63, l = tid & 15, quad = (tid >> 4) & 3;
    const u16* ab = att_t + (size_t)b * (PP * PP * C);

    auto stage = [&](int cib, int bufi) {
        u16* base = &in_s[bufi][w * 102 * 8];
        const u16* gsrc = ab + cib * 32 + w * 8;
#pragma unroll
        for (int t = 0; t < 2; t++) {
            int idx = t * 64 + lane;
            int r = idx / 34, xp = idx - r * 34;
            if (t == 0 || lane < 38)
                __builtin_amdgcn_global_load_lds(
                    (const __attribute__((address_space(1))) void*)(gsrc + (size_t)((y + r) * PP + x0 + xp) * C),
                    (__attribute__((address_space(3))) void*)(base + (size_t)t * 64 * 8), 16, 0, 0);
        }
    };

    f32x4 accr[2][2];
#pragma unroll
    for (int cf = 0; cf < 2; cf++)
#pragma unroll
        for (int nf = 0; nf < 2; nf++) accr[cf][nf] = (f32x4){0.f, 0.f, 0.f, 0.f};
    int cow = w * 32;

    stage(0, 0);
    __syncthreads();
#pragma unroll
    for (int cib = 0; cib < 4; cib++) {
        if (cib < 3) stage(cib + 1, (cib + 1) & 1);
        s16x8 wf[9][2];
#pragma unroll
        for (int pos = 0; pos < 9; pos++)
#pragma unroll
            for (int cf = 0; cf < 2; cf++)
                wf[pos][cf] = *(const s16x8*)&wt[((size_t)(pos * 4 + cib) * C + cow + cf * 16 + l) * 32 + quad * 8];
        const u16* bufc = &in_s[cib & 1][0];
#pragma unroll
        for (int ky = 0; ky < 3; ky++)
#pragma unroll
            for (int kx = 0; kx < 3; kx++) {
                int pos = ky * 3 + kx;
#pragma unroll
                for (int nf = 0; nf < 2; nf++) {
                    s16x8 inf = *(const s16x8*)&bufc[(quad * 102 + ky * 34 + nf * 16 + l + kx) * 8];
                    accr[0][nf] = __builtin_amdgcn_mfma_f32_16x16x32_bf16(wf[pos][0], inf, accr[0][nf], 0, 0, 0);
                    accr[1][nf] = __builtin_amdgcn_mfma_f32_16x16x32_bf16(wf[pos][1], inf, accr[1][nf], 0, 0, 0);
                }
            }
        __syncthreads();
    }

    float g = gamma[0];
    float* ob = out + (size_t)b * C * NN;
    const float* sb = sr + (size_t)b * C * NN;
#pragma unroll
    for (int cf = 0; cf < 2; cf++)
#pragma unroll
        for (int r = 0; r < 4; r++) {
            int co = cow + cf * 16 + quad * 4 + r;
            float bias = bp[co];
#pragma unroll
            for (int nf = 0; nf < 2; nf++) {
                size_t oo = (size_t)co * NN + y * 64 + x0 + nf * 16 + l;
                ob[oo] = sb[oo] + g * (accr[cf][nf][r] + bias);
            }
        }
}

// ---------------------------------------------------------------------------
extern "C" void kernel_launch(void* const* d_in, const int* in_sizes, int n_in,
                              void* d_out, int out_size, void* d_ws, size_t ws_size,
                              hipStream_t stream) {
    const float* sr    = (const float*)d_in[0];
    const float* ctx   = (const float*)d_in[1];
    const float* Wq    = (const float*)d_in[2];
    const float* bq    = (const float*)d_in[3];
    const float* Wk    = (const float*)d_in[4];
    const float* bk    = (const float*)d_in[5];
    const float* Wv    = (const float*)d_in[6];
    const float* bv    = (const float*)d_in[7];
    const float* Wp    = (const float*)d_in[8];
    const float* bp    = (const float*)d_in[9];
    const float* gamma = (const float*)d_in[10];
    float* out = (float*)d_out;

    // ws layout (bytes), ~46.7 MB:
    //   att_t bf16 [B][66][66][C]          @0      (4,460,544)
    //   part bf16 [4][B][C][N]             @5 MB   (16 MB)
    //   lpart f32 [4][B][N]                @21 MB  (256 KB)
    //   ctx_t bf16 [B][N][CCH]             @22 MB  (8 MB)
    //   sr_t bf16 [B][N][C]                @30 MB  (4 MB)
    //   q_t / k_t / v bf16                 @34/38/42 MB (4 MB each)
    //   wt + w_bf                          @46 MB
    char* wsb = (char*)d_ws;
    u16*   att_t  = (u16*)wsb;
    u16*   part   = (u16*)(wsb + (5u << 20));
    float* lpart  = (float*)(wsb + (21u << 20));
    u16*   ctx_t  = (u16*)(wsb + (22u << 20));
    u16*   sr_t   = (u16*)(wsb + (30u << 20));
    u16*   q_t    = (u16*)(wsb + (34u << 20));
    u16*   k_t    = (u16*)(wsb + (38u << 20));
    u16*   v_bf   = (u16*)(wsb + (42u << 20));
    u16*   wt     = (u16*)(wsb + (46u << 20));
    u16*   w_bf   = (u16*)(wsb + (46u << 20) + (512u << 10));

    prep_all<<<dim3(3009), 256, 0, stream>>>(ctx, sr, Wq, Wk, Wv, Wp,
                                             ctx_t, sr_t, w_bf, wt,
                                             (uint4*)att_t);
    proj_all<<<dim3(32, NB, 3), 256, 0, stream>>>(sr_t, ctx_t, w_bf, bq, bk, bv,
                                                  q_t, k_t, v_bf);
    flash_mfma<<<dim3(512), 256, 0, stream>>>(q_t, k_t, v_bf, part, lpart);
    flash_combine<<<dim3(64, NB), 256, 0, stream>>>(part, lpart, att_t);
    conv3x3_mfma<<<dim3(512), 256, 0, stream>>>(att_t, wt, bp, sr, gamma, out);
}

// Round 10
// 161.932 us; speedup vs baseline: 1.6521x; 1.0398x over previous
//
#include <hip/hip_runtime.h>
#include <math.h>

// Problem constants
#define NB 4      // batch
#define C  128    // channels (q/k/v/out)
#define CCH 256   // context channels
#define HH 64
#define WW 64
#define NN 4096   // HH*WW
#define HC 32
#define WC 32
#define PP 66     // padded spatial dim for conv input (64 + 2 halo)
#define LOG2E 1.44269504088896f
#define NSPLIT 4  // flash split-K factor

typedef unsigned short u16;
typedef unsigned int uint32;
typedef short s16x8 __attribute__((ext_vector_type(8)));    // 8 bf16 = MFMA A/B frag
typedef float f32x4 __attribute__((ext_vector_type(4)));    // 16x16 MFMA C/D frag
typedef float f32x16 __attribute__((ext_vector_type(16)));  // 32x32 MFMA C/D frag

// raw v_exp_f32 (library exp2f carries denormal guards without -ffast-math)
#if __has_builtin(__builtin_amdgcn_exp2f)
#define EXP2(x) __builtin_amdgcn_exp2f(x)
#else
#define EXP2(x) __expf((x) * 0.69314718056f)
#endif

// fp32 -> bf16 round-to-nearest-even
__device__ __forceinline__ u16 f2bf(float f) {
    uint32 u = __float_as_uint(f);
    u += 0x7fffu + ((u >> 16) & 1u);
    return (u16)(u >> 16);
}
__device__ __forceinline__ float bf2f(u16 h) {
    return __uint_as_float((uint32)h << 16);
}

// ---------------------------------------------------------------------------
// 1) prep_all: ONE launch fusing upsample+tcast / sr tcast / weight prep /
//    att_t border zero.
// ---------------------------------------------------------------------------
__global__ __launch_bounds__(256) void prep_all(const float* __restrict__ ctx,
                                                const float* __restrict__ sr,
                                                const float* __restrict__ Wq,
                                                const float* __restrict__ Wk,
                                                const float* __restrict__ Wv,
                                                const float* __restrict__ Wp,
                                                u16* __restrict__ ctx_t,
                                                u16* __restrict__ sr_t,
                                                u16* __restrict__ wbf,
                                                u16* __restrict__ wt,
                                                uint4* __restrict__ att_z) {
    __shared__ float smem[2 * 32 * 130];
    int blk = blockIdx.x;
    int tid = threadIdx.x;

    if (blk < 512) {
        float (*ls)[32][130] = (float(*)[32][130])smem;
        int y = blk & 63;
        int cch = (blk >> 6) & 1;
        int b = blk >> 7;
        float sy = y * 0.5f - 0.25f;
        int y0 = (int)floorf(sy);
        float wy = sy - (float)y0;
        int y0c = y0 < 0 ? 0 : y0;
        int y1c = (y0 + 1 > HC - 1) ? HC - 1 : y0 + 1;
#pragma unroll
        for (int t = 0; t < 4; t++) {
            int CI = t * 256 + tid;
            int cc = CI >> 3, xq = CI & 7;
            const float* s = ctx + (size_t)(b * CCH + cch * 128 + cc) * (HC * WC);
            float4 v0 = *(const float4*)(s + y0c * WC + xq * 4);
            float4 v1 = *(const float4*)(s + y1c * WC + xq * 4);
            ls[0][xq * 4 + 0][cc] = v0.x; ls[0][xq * 4 + 1][cc] = v0.y;
            ls[0][xq * 4 + 2][cc] = v0.z; ls[0][xq * 4 + 3][cc] = v0.w;
            ls[1][xq * 4 + 0][cc] = v1.x; ls[1][xq * 4 + 1][cc] = v1.y;
            ls[1][xq * 4 + 2][cc] = v1.z; ls[1][xq * 4 + 3][cc] = v1.w;
        }
        __syncthreads();
        int occ = tid & 127, xh = tid >> 7;
        u16* ob = ctx_t + ((size_t)b * NN + (size_t)y * 64) * CCH + cch * 128 + occ;
        float wy1 = 1.f - wy;
#pragma unroll
        for (int xi = 0; xi < 32; xi++) {
            int x = xi * 2 + xh;
            float sx = x * 0.5f - 0.25f;
            int x0 = (int)floorf(sx);
            float wx = sx - (float)x0;
            int x0c = x0 < 0 ? 0 : x0;
            int x1c = (x0 + 1 > WC - 1) ? WC - 1 : x0 + 1;
            float v00 = ls[0][x0c][occ], v01 = ls[0][x1c][occ];
            float v10 = ls[1][x0c][occ], v11 = ls[1][x1c][occ];
            float val = wy1 * ((1.f - wx) * v00 + wx * v01)
                      + wy  * ((1.f - wx) * v10 + wx * v11);
            ob[(size_t)x * CCH] = f2bf(val);
        }
    } else if (blk < 1024) {
        float* ls = smem;
        int idx = blk - 512;
        int n0 = (idx & 63) * 64;
        int ci0 = ((idx >> 6) & 1) * 64;
        int b = idx >> 7;
        const float* inb = sr + ((size_t)b * C + ci0) * NN + n0;
#pragma unroll
        for (int L = 0; L < 4; L++) {
            int fc = tid + L * 256;
            int nc = fc & 15, ci = fc >> 4;
            float4 v = *(const float4*)(inb + (size_t)ci * NN + nc * 4);
            float* d = &ls[ci * 65 + nc * 4];
            d[0] = v.x; d[1] = v.y; d[2] = v.z; d[3] = v.w;
        }
        __syncthreads();
        u16* ob = sr_t + ((size_t)b * NN + n0) * C + ci0;
#pragma unroll
        for (int j = 0; j < 16; j++) {
            int o = tid + j * 256;
            int ci = o & 63, n = o >> 6;
            ob[(size_t)n * C + ci] = f2bf(ls[ci * 65 + n]);
        }
    } else if (blk < 1920) {
        int i = (blk - 1024) * 256 + tid;
        if (i < 81920) {
            float v;
            if (i < 16384) v = Wq[i] * LOG2E;
            else if (i < 49152) v = Wk[i - 16384];
            else v = Wv[i - 49152];
            wbf[i] = f2bf(v);
        } else {
            int idx = i - 81920;
            int ciin = idx & 31;
            int co = (idx >> 5) & 127;
            int cb = (idx >> 12) & 3;
            int pos = idx >> 14;
            int ky = pos / 3, kx = pos - ky * 3;
            int ci = cb * 32 + ciin;
            wt[idx] = f2bf(Wp[((size_t)(co * C + ci) * 3 + ky) * 3 + kx]);
        }
    } else {
        int i = (blk - 1920) * 256 + tid;
        if (i < 278784) att_z[i] = make_uint4(0, 0, 0, 0);
    }
}

// ---------------------------------------------------------------------------
// 2) Fused projection GEMM (q/k/v by blockIdx.z), LDS-staged. (r6, proven)
// ---------------------------------------------------------------------------
__global__ __launch_bounds__(256) void proj_all(const u16* __restrict__ sr_t,
                                                const u16* __restrict__ ctx_t,
                                                const u16* __restrict__ wbf,
                                                const float* __restrict__ bq,
                                                const float* __restrict__ bk,
                                                const float* __restrict__ bv,
                                                u16* __restrict__ q_t,
                                                u16* __restrict__ k_t,
                                                u16* __restrict__ v_bf) {
    __shared__ u16 xs[128 * 64];
    __shared__ u16 wsm[128 * 64];
    int z = blockIdx.z;
    int b = blockIdx.y;
    int n0 = blockIdx.x * 128;
    int Cin = (z == 0) ? C : CCH;
    const u16* xb = (z == 0 ? sr_t : ctx_t) + (size_t)b * NN * Cin;
    const u16* wb = wbf + (z == 0 ? 0 : (z == 1 ? 16384 : 49152));
    const float* bias = (z == 0) ? bq : (z == 1 ? bk : bv);
    float bsc = (z == 0) ? LOG2E : 1.0f;
    bool vmode = (z == 2);

    int tid = threadIdx.x;
    int w = tid >> 6, lane = tid & 63, l31 = lane & 31, half = lane >> 5;
    int xh = w >> 1, wh = w & 1;

    f32x16 acc[2][2];
#pragma unroll
    for (int xt = 0; xt < 2; xt++)
#pragma unroll
        for (int wt2 = 0; wt2 < 2; wt2++)
#pragma unroll
            for (int i = 0; i < 16; i++) acc[xt][wt2][i] = 0.f;

    int nchunks = Cin >> 6;
    for (int c0i = 0; c0i < nchunks; c0i++) {
        int c0 = c0i * 64;
        __syncthreads();
#pragma unroll
        for (int t = 0; t < 4; t++) {
            int CI = t * 256 + tid;
            int row = CI >> 3, sl = CI & 7;
            int lc = sl ^ (row & 7);
            __builtin_amdgcn_global_load_lds(
                (const __attribute__((address_space(1))) void*)(xb + (size_t)(n0 + row) * Cin + c0 + lc * 8),
                (__attribute__((address_space(3))) void*)&xs[(size_t)CI * 8], 16, 0, 0);
        }
#pragma unroll
        for (int t = 0; t < 4; t++) {
            int CI = t * 256 + tid;
            int co = CI >> 3, sl = CI & 7;
            int lc = sl ^ (co & 7);
            __builtin_amdgcn_global_load_lds(
                (const __attribute__((address_space(1))) void*)(wb + (size_t)co * Cin + c0 + lc * 8),
                (__attribute__((address_space(3))) void*)&wsm[(size_t)CI * 8], 16, 0, 0);
        }
        __syncthreads();
#pragma unroll
        for (int kg = 0; kg < 4; kg++) {
            int pc = ((kg * 2 + half) ^ (l31 & 7)) * 8;
            s16x8 xf[2], wf2[2];
#pragma unroll
            for (int xt = 0; xt < 2; xt++)
                xf[xt] = *(const s16x8*)&xs[(xh * 64 + xt * 32 + l31) * 64 + pc];
#pragma unroll
            for (int wt2 = 0; wt2 < 2; wt2++)
                wf2[wt2] = *(const s16x8*)&wsm[(wh * 64 + wt2 * 32 + l31) * 64 + pc];
#pragma unroll
            for (int xt = 0; xt < 2; xt++)
#pragma unroll
                for (int wt2 = 0; wt2 < 2; wt2++) {
                    if (vmode)
                        acc[xt][wt2] = __builtin_amdgcn_mfma_f32_32x32x16_bf16(wf2[wt2], xf[xt], acc[xt][wt2], 0, 0, 0);
                    else
                        acc[xt][wt2] = __builtin_amdgcn_mfma_f32_32x32x16_bf16(xf[xt], wf2[wt2], acc[xt][wt2], 0, 0, 0);
                }
        }
    }

    if (!vmode) {
        u16* ot = (z == 0 ? q_t : k_t) + (size_t)b * NN * C;
        float bv2[2];
#pragma unroll
        for (int wt2 = 0; wt2 < 2; wt2++) bv2[wt2] = bias[wh * 64 + wt2 * 32 + l31] * bsc;
#pragma unroll
        for (int xt = 0; xt < 2; xt++)
#pragma unroll
            for (int r = 0; r < 16; r++) {
                int n = n0 + xh * 64 + xt * 32 + (r & 3) + 8 * (r >> 2) + 4 * half;
#pragma unroll
                for (int wt2 = 0; wt2 < 2; wt2++)
                    ot[(size_t)n * C + wh * 64 + wt2 * 32 + l31] = f2bf(acc[xt][wt2][r] + bv2[wt2]);
            }
    } else {
        u16* ov = v_bf + (size_t)b * C * NN;
#pragma unroll
        for (int wt2 = 0; wt2 < 2; wt2++)
#pragma unroll
            for (int r = 0; r < 16; r++) {
                int co = wh * 64 + wt2 * 32 + (r & 3) + 8 * (r >> 2) + 4 * half;
                float bvv = bias[co];
#pragma unroll
                for (int xt = 0; xt < 2; xt++) {
                    int n = n0 + xh * 64 + xt * 32 + l31;
                    ov[(size_t)co * NN + n] = f2bf(acc[xt][wt2][r] + bvv);
                }
            }
    }
}

// ---------------------------------------------------------------------------
// 3) Flash attention v10: r9 (no atomics) + ONE barrier/iter (K+V double-
//    buffered, prefetch issued at iter start with a full iter of lead) +
//    raw v_exp_f32 + single live st tile (register diet).
//    Split-K x4, grid 512 = 2 blocks/CU. LDS 64 KB.
// ---------------------------------------------------------------------------
__global__ __launch_bounds__(256) void flash_mfma(const u16* __restrict__ qt_p,
                                                  const u16* __restrict__ kt_p,
                                                  const u16* __restrict__ vt_p,
                                                  u16* __restrict__ part,
                                                  float* __restrict__ lpart) {
    __shared__ u16 ks[2][64 * 128];   // [key][ch] chunk-XOR16, 2x16 KB
    __shared__ u16 vs[2][128 * 64];   // [ch][key] chunk-XOR8,  2x16 KB

    int ib = blockIdx.x;
    int b = (ib & 7) >> 1;                       // batch -> XCD pair
    int rest = ((ib >> 3) << 1) | (ib & 1);      // 0..127
    int qtile = rest >> 2;                       // 0..31
    int split = rest & 3;                        // 0..3
    int n0 = qtile * 128;
    int tid = threadIdx.x;
    int w = tid >> 6, lane = tid & 63, l31 = lane & 31, half = lane >> 5;

    const u16* qtb = qt_p + (size_t)b * NN * C;
    const u16* ktb = kt_p + (size_t)b * NN * C;
    const u16* vtb = vt_p + (size_t)b * C * NN;

    auto stageK = [&](int buf, int m0) {
#pragma unroll
        for (int t = 0; t < 4; t++) {
            int CI = (w * 4 + t) * 64 + lane;
            int r = CI >> 4;
            int lc = (CI & 15) ^ (r & 15);
            __builtin_amdgcn_global_load_lds(
                (const __attribute__((address_space(1))) void*)(ktb + (size_t)(m0 + r) * C + lc * 8),
                (__attribute__((address_space(3))) void*)&ks[buf][(w * 4 + t) * 512], 16, 0, 0);
        }
    };
    auto stageV = [&](int buf, int m0) {
#pragma unroll
        for (int t = 0; t < 4; t++) {
            int CI = (w * 4 + t) * 64 + lane;
            int c = CI >> 3;
            int lc = (CI & 7) ^ (c & 7);
            __builtin_amdgcn_global_load_lds(
                (const __attribute__((address_space(1))) void*)(vtb + (size_t)c * NN + m0 + lc * 8),
                (__attribute__((address_space(3))) void*)&vs[buf][(w * 4 + t) * 512], 16, 0, 0);
        }
    };

    // Q B-fragments in registers (reused all iterations)
    int qrow = n0 + w * 32 + l31;
    s16x8 qf[8];
#pragma unroll
    for (int kg = 0; kg < 8; kg++)
        qf[kg] = *(const s16x8*)(qtb + (size_t)qrow * C + kg * 16 + half * 8);

    int m_base = split * 1024;
    stageK(0, m_base);
    stageV(0, m_base);
    __syncthreads();

    f32x16 oacc[4];
#pragma unroll
    for (int mt = 0; mt < 4; mt++)
#pragma unroll
        for (int i = 0; i < 16; i++) oacc[mt][i] = 0.f;
    float lsum = 0.f;

    for (int it = 0; it < 16; it++) {
        int buf = it & 1;
        int m0 = m_base + it * 64;
        if (it < 15) {                            // prefetch next tile; a full
            stageK(buf ^ 1, m0 + 64);             // iteration of compute covers
            stageV(buf ^ 1, m0 + 64);             // the vmcnt drain at barrier
        }
        const u16* ksb = &ks[buf][0];
        const u16* vsb = &vs[buf][0];

#pragma unroll
        for (int kmt = 0; kmt < 2; kmt++) {
            // ---- S^T = K·Q for one 32-key tile ----
            f32x16 st;
#pragma unroll
            for (int i = 0; i < 16; i++) st[i] = 0.f;
#pragma unroll
            for (int kg = 0; kg < 8; kg++) {
                int pc = ((kg * 2 + half) ^ (l31 & 15)) * 8;
                s16x8 kf = *(const s16x8*)&ksb[(kmt * 32 + l31) * 128 + pc];
                st = __builtin_amdgcn_mfma_f32_32x32x16_bf16(kf, qf[kg], st, 0, 0, 0);
            }
            // ---- exp2 (raw) + pack to bf16 pairs ----
            uint32 A[4], B4[4];
#pragma unroll
            for (int rg = 0; rg < 4; rg++) {
                float e0 = EXP2(st[rg * 4 + 0]);
                float e1 = EXP2(st[rg * 4 + 1]);
                float e2 = EXP2(st[rg * 4 + 2]);
                float e3 = EXP2(st[rg * 4 + 3]);
                lsum += (e0 + e1) + (e2 + e3);
                A[rg]  = __builtin_amdgcn_perm(__float_as_uint(e1), __float_as_uint(e0), 0x07060302u);
                B4[rg] = __builtin_amdgcn_perm(__float_as_uint(e3), __float_as_uint(e2), 0x07060302u);
            }
            // ---- register P-transpose (shfl_xor 32) + PV ----
#pragma unroll
            for (int s = 0; s < 2; s++) {
                uint32 sendA = half ? A[2 * s] : A[2 * s + 1];
                uint32 sendB = half ? B4[2 * s] : B4[2 * s + 1];
                uint32 rA = __shfl_xor(sendA, 32);
                uint32 rB = __shfl_xor(sendB, 32);
                uint32 oA = half ? A[2 * s + 1] : A[2 * s];
                uint32 oB = half ? B4[2 * s + 1] : B4[2 * s];
                union { uint32 u[4]; s16x8 v; } pu;
                pu.u[0] = half ? rA : oA;
                pu.u[1] = half ? rB : oB;
                pu.u[2] = half ? oA : rA;
                pu.u[3] = half ? oB : rB;
                s16x8 pf = pu.v;
                int kgp = kmt * 2 + s;
                int pcv = ((kgp * 2 + half) ^ (l31 & 7)) * 8;
#pragma unroll
                for (int mt = 0; mt < 4; mt++) {
                    s16x8 vf = *(const s16x8*)&vsb[(mt * 32 + l31) * 64 + pcv];
                    oacc[mt] = __builtin_amdgcn_mfma_f32_32x32x16_bf16(vf, pf, oacc[mt], 0, 0, 0);
                }
            }
        }
        __syncthreads();   // all waves done with buf; next iter overwrites buf^1's pair
    }

    // ---- epilogue: plain coalesced stores of bf16 partials ----
    float lt = lsum + __shfl_xor(lsum, 32);
    if (half == 0) lpart[(size_t)split * NB * NN + (size_t)b * NN + qrow] = lt;
    u16* pb = part + ((size_t)split * NB + b) * (size_t)C * NN;
#pragma unroll
    for (int mt = 0; mt < 4; mt++)
#pragma unroll
        for (int r = 0; r < 16; r++) {
            int c = mt * 32 + (r & 3) + 8 * (r >> 2) + 4 * half;
            pb[(size_t)c * NN + n0 + w * 32 + l31] = f2bf(oacc[mt][r]);
        }
}

// ---------------------------------------------------------------------------
// 4) Combine: att_t[b][y+1][x+1][c] = bf16( sum_s part / sum_s lpart )
// ---------------------------------------------------------------------------
__global__ __launch_bounds__(256) void flash_combine(const u16* __restrict__ part,
                                                     const float* __restrict__ lpart,
                                                     u16* __restrict__ att_t) {
    __shared__ u16 ts[128 * 66];
    __shared__ float linv[64];
    int b = blockIdx.y;
    int nt = blockIdx.x;
    int n0 = nt * 64;
    int tid = threadIdx.x;
    if (tid < 64) {
        float s = 0.f;
#pragma unroll
        for (int sp = 0; sp < NSPLIT; sp++)
            s += lpart[(size_t)sp * NB * NN + (size_t)b * NN + n0 + tid];
        linv[tid] = 1.0f / s;
    }
    __syncthreads();
#pragma unroll
    for (int j = 0; j < 32; j++) {
        int e = tid + j * 256;
        int n = e & 63, c = e >> 6;
        float o = 0.f;
#pragma unroll
        for (int sp = 0; sp < NSPLIT; sp++)
            o += bf2f(part[((size_t)sp * NB + b) * (size_t)C * NN + (size_t)c * NN + n0 + n]);
        ts[c * 66 + n] = f2bf(o * linv[n]);
    }
    __syncthreads();
    u16* ob = att_t + ((size_t)b * PP * PP + (size_t)(nt + 1) * PP + 1) * C;
#pragma unroll
    for (int j = 0; j < 32; j++) {
        int o = tid + j * 256;
        int c = o & 127, n = o >> 7;
        ob[(size_t)n * C + c] = ts[c * 66 + n];
    }
}

// ---------------------------------------------------------------------------
// 5) Implicit-GEMM MFMA conv3x3 + residual (proven).
// ---------------------------------------------------------------------------
__global__ __launch_bounds__(256) void conv3x3_mfma(const u16* __restrict__ att_t,
                                                    const u16* __restrict__ wt,
                                                    const float* __restrict__ bp,
                                                    const float* __restrict__ sr,
                                                    const float* __restrict__ gamma,
                                                    float* __restrict__ out) {
    __shared__ u16 in_s[2][4 * 102 * 8];
    int ib = blockIdx.x;
    int b = (ib & 7) >> 1;
    int rr = ((ib >> 3) << 1) | (ib & 1);
    int y = rr >> 1;
    int x0 = (rr & 1) * 32;
    int tid = threadIdx.x;
    int w = tid >> 6, lane = tid & 63, l = tid & 15, quad = (tid >> 4) & 3;
    const u16* ab = att_t + (size_t)b * (PP * PP * C);

    auto stage = [&](int cib, int bufi) {
        u16* base = &in_s[bufi][w * 102 * 8];
        const u16* gsrc = ab + cib * 32 + w * 8;
#pragma unroll
        for (int t = 0; t < 2; t++) {
            int idx = t * 64 + lane;
            int r = idx / 34, xp = idx - r * 34;
            if (t == 0 || lane < 38)
                __builtin_amdgcn_global_load_lds(
                    (const __attribute__((address_space(1))) void*)(gsrc + (size_t)((y + r) * PP + x0 + xp) * C),
                    (__attribute__((address_space(3))) void*)(base + (size_t)t * 64 * 8), 16, 0, 0);
        }
    };

    f32x4 accr[2][2];
#pragma unroll
    for (int cf = 0; cf < 2; cf++)
#pragma unroll
        for (int nf = 0; nf < 2; nf++) accr[cf][nf] = (f32x4){0.f, 0.f, 0.f, 0.f};
    int cow = w * 32;

    stage(0, 0);
    __syncthreads();
#pragma unroll
    for (int cib = 0; cib < 4; cib++) {
        if (cib < 3) stage(cib + 1, (cib + 1) & 1);
        s16x8 wf[9][2];
#pragma unroll
        for (int pos = 0; pos < 9; pos++)
#pragma unroll
            for (int cf = 0; cf < 2; cf++)
                wf[pos][cf] = *(const s16x8*)&wt[((size_t)(pos * 4 + cib) * C + cow + cf * 16 + l) * 32 + quad * 8];
        const u16* bufc = &in_s[cib & 1][0];
#pragma unroll
        for (int ky = 0; ky < 3; ky++)
#pragma unroll
            for (int kx = 0; kx < 3; kx++) {
                int pos = ky * 3 + kx;
#pragma unroll
                for (int nf = 0; nf < 2; nf++) {
                    s16x8 inf = *(const s16x8*)&bufc[(quad * 102 + ky * 34 + nf * 16 + l + kx) * 8];
                    accr[0][nf] = __builtin_amdgcn_mfma_f32_16x16x32_bf16(wf[pos][0], inf, accr[0][nf], 0, 0, 0);
                    accr[1][nf] = __builtin_amdgcn_mfma_f32_16x16x32_bf16(wf[pos][1], inf, accr[1][nf], 0, 0, 0);
                }
            }
        __syncthreads();
    }

    float g = gamma[0];
    float* ob = out + (size_t)b * C * NN;
    const float* sb = sr + (size_t)b * C * NN;
#pragma unroll
    for (int cf = 0; cf < 2; cf++)
#pragma unroll
        for (int r = 0; r < 4; r++) {
            int co = cow + cf * 16 + quad * 4 + r;
            float bias = bp[co];
#pragma unroll
            for (int nf = 0; nf < 2; nf++) {
                size_t oo = (size_t)co * NN + y * 64 + x0 + nf * 16 + l;
                ob[oo] = sb[oo] + g * (accr[cf][nf][r] + bias);
            }
        }
}

// ---------------------------------------------------------------------------
extern "C" void kernel_launch(void* const* d_in, const int* in_sizes, int n_in,
                              void* d_out, int out_size, void* d_ws, size_t ws_size,
                              hipStream_t stream) {
    const float* sr    = (const float*)d_in[0];
    const float* ctx   = (const float*)d_in[1];
    const float* Wq    = (const float*)d_in[2];
    const float* bq    = (const float*)d_in[3];
    const float* Wk    = (const float*)d_in[4];
    const float* bk    = (const float*)d_in[5];
    const float* Wv    = (const float*)d_in[6];
    const float* bv    = (const float*)d_in[7];
    const float* Wp    = (const float*)d_in[8];
    const float* bp    = (const float*)d_in[9];
    const float* gamma = (const float*)d_in[10];
    float* out = (float*)d_out;

    char* wsb = (char*)d_ws;
    u16*   att_t  = (u16*)wsb;
    u16*   part   = (u16*)(wsb + (5u << 20));
    float* lpart  = (float*)(wsb + (21u << 20));
    u16*   ctx_t  = (u16*)(wsb + (22u << 20));
    u16*   sr_t   = (u16*)(wsb + (30u << 20));
    u16*   q_t    = (u16*)(wsb + (34u << 20));
    u16*   k_t    = (u16*)(wsb + (38u << 20));
    u16*   v_bf   = (u16*)(wsb + (42u << 20));
    u16*   wt     = (u16*)(wsb + (46u << 20));
    u16*   w_bf   = (u16*)(wsb + (46u << 20) + (512u << 10));

    prep_all<<<dim3(3009), 256, 0, stream>>>(ctx, sr, Wq, Wk, Wv, Wp,
                                             ctx_t, sr_t, w_bf, wt,
                                             (uint4*)att_t);
    proj_all<<<dim3(32, NB, 3), 256, 0, stream>>>(sr_t, ctx_t, w_bf, bq, bk, bv,
                                                  q_t, k_t, v_bf);
    flash_mfma<<<dim3(512), 256, 0, stream>>>(q_t, k_t, v_bf, part, lpart);
    flash_combine<<<dim3(64, NB), 256, 0, stream>>>(part, lpart, att_t);
    conv3x3_mfma<<<dim3(512), 256, 0, stream>>>(att_t, wt, bp, sr, gamma, out);
}

// Round 11
// 161.102 us; speedup vs baseline: 1.6606x; 1.0052x over previous
//
#include <hip/hip_runtime.h>
#include <math.h>

// Problem constants
#define NB 4      // batch
#define C  128    // channels (q/k/v/out)
#define CCH 256   // context channels
#define HH 64
#define WW 64
#define NN 4096   // HH*WW
#define NS 1024   // source-resolution pixel count (32*32)
#define HC 32
#define WC 32
#define PP 66     // padded spatial dim for conv input (64 + 2 halo)
#define LOG2E 1.44269504088896f
#define NSPLIT 4  // flash split-K factor

typedef unsigned short u16;
typedef unsigned int uint32;
typedef short s16x8 __attribute__((ext_vector_type(8)));    // 8 bf16 = MFMA A/B frag
typedef float f32x4 __attribute__((ext_vector_type(4)));    // 16x16 MFMA C/D frag
typedef float f32x16 __attribute__((ext_vector_type(16)));  // 32x32 MFMA C/D frag

#if __has_builtin(__builtin_amdgcn_exp2f)
#define EXP2(x) __builtin_amdgcn_exp2f(x)
#else
#define EXP2(x) __expf((x) * 0.69314718056f)
#endif

__device__ __forceinline__ u16 f2bf(float f) {
    uint32 u = __float_as_uint(f);
    u += 0x7fffu + ((u >> 16) & 1u);
    return (u16)(u >> 16);
}
__device__ __forceinline__ float bf2f(u16 h) {
    return __uint_as_float((uint32)h << 16);
}

// ---------------------------------------------------------------------------
// 1) prep2: [0,256) ctx transpose-cast (source res) -> ctx_s bf16 [b][1024][cc]
//    [256,768) sr transpose-cast -> sr_t bf16 [b][4096][C]
//    [768,1664) weight prep   [1664,2753) zero att_t
// ---------------------------------------------------------------------------
__global__ __launch_bounds__(256) void prep2(const float* __restrict__ ctx,
                                             const float* __restrict__ sr,
                                             const float* __restrict__ Wq,
                                             const float* __restrict__ Wk,
                                             const float* __restrict__ Wv,
                                             const float* __restrict__ Wp,
                                             u16* __restrict__ ctx_s,
                                             u16* __restrict__ sr_t,
                                             u16* __restrict__ wbf,
                                             u16* __restrict__ wt,
                                             uint4* __restrict__ att_z) {
    __shared__ float ls[64 * 65];
    int blk = blockIdx.x;
    int tid = threadIdx.x;

    if (blk < 256) {
        // ctx f32 [b][cc][1024] -> ctx_s bf16 [b][1024][cc], 64x64 tiles
        int idx = blk;
        int n0 = (idx & 15) * 64;
        int ci0 = ((idx >> 4) & 3) * 64;
        int b = idx >> 6;
        const float* inb = ctx + ((size_t)b * CCH + ci0) * NS + n0;
#pragma unroll
        for (int L = 0; L < 4; L++) {
            int fc = tid + L * 256;
            int nc = fc & 15, ci = fc >> 4;
            float4 v = *(const float4*)(inb + (size_t)ci * NS + nc * 4);
            float* d = &ls[ci * 65 + nc * 4];
            d[0] = v.x; d[1] = v.y; d[2] = v.z; d[3] = v.w;
        }
        __syncthreads();
        u16* ob = ctx_s + ((size_t)b * NS + n0) * CCH + ci0;
#pragma unroll
        for (int j = 0; j < 16; j++) {
            int o = tid + j * 256;
            int ci = o & 63, n = o >> 6;
            ob[(size_t)n * CCH + ci] = f2bf(ls[ci * 65 + n]);
        }
    } else if (blk < 768) {
        // sr f32 [b][C][4096] -> sr_t bf16 [b][4096][C]
        int idx = blk - 256;
        int n0 = (idx & 63) * 64;
        int ci0 = ((idx >> 6) & 1) * 64;
        int b = idx >> 7;
        const float* inb = sr + ((size_t)b * C + ci0) * NN + n0;
#pragma unroll
        for (int L = 0; L < 4; L++) {
            int fc = tid + L * 256;
            int nc = fc & 15, ci = fc >> 4;
            float4 v = *(const float4*)(inb + (size_t)ci * NN + nc * 4);
            float* d = &ls[ci * 65 + nc * 4];
            d[0] = v.x; d[1] = v.y; d[2] = v.z; d[3] = v.w;
        }
        __syncthreads();
        u16* ob = sr_t + ((size_t)b * NN + n0) * C + ci0;
#pragma unroll
        for (int j = 0; j < 16; j++) {
            int o = tid + j * 256;
            int ci = o & 63, n = o >> 6;
            ob[(size_t)n * C + ci] = f2bf(ls[ci * 65 + n]);
        }
    } else if (blk < 1664) {
        int i = (blk - 768) * 256 + tid;   // 0..229375
        if (i < 81920) {
            float v;
            if (i < 16384) v = Wq[i] * LOG2E;
            else if (i < 49152) v = Wk[i - 16384];
            else v = Wv[i - 49152];
            wbf[i] = f2bf(v);
        } else {
            int idx = i - 81920;
            int ciin = idx & 31;
            int co = (idx >> 5) & 127;
            int cb = (idx >> 12) & 3;
            int pos = idx >> 14;
            int ky = pos / 3, kx = pos - ky * 3;
            int ci = cb * 32 + ciin;
            wt[idx] = f2bf(Wp[((size_t)(co * C + ci) * 3 + ky) * 3 + kx]);
        }
    } else {
        int i = (blk - 1664) * 256 + tid;   // 0..278783
        if (i < 278784) att_z[i] = make_uint4(0, 0, 0, 0);
    }
}

// ---------------------------------------------------------------------------
// 2) proj_all2: x<32 -> q projection (N=4096, Cin=128, sr_t);
//               x>=32 -> K AND V from one staged ctx_s tile (N=1024, Cin=256).
//    kv: 64 source px x 128 co, both outputs; ctx read ONCE.
// ---------------------------------------------------------------------------
__global__ __launch_bounds__(256) void proj_all2(const u16* __restrict__ sr_t,
                                                 const u16* __restrict__ ctx_s,
                                                 const u16* __restrict__ wbf,
                                                 const float* __restrict__ bq,
                                                 const float* __restrict__ bk,
                                                 const float* __restrict__ bv,
                                                 u16* __restrict__ q_t,
                                                 u16* __restrict__ k_s,
                                                 u16* __restrict__ v_s) {
    __shared__ u16 xs[128 * 64];      // 16 KB (kv uses first 8 KB)
    __shared__ u16 wsm[2][128 * 64];  // 32 KB
    int b = blockIdx.y;
    int tid = threadIdx.x;
    int w = tid >> 6, lane = tid & 63, l31 = lane & 31, half = lane >> 5;
    int xh = w >> 1, wh = w & 1;

    if (blockIdx.x < 32) {
        // ---- Q: 128 n x 128 co, Cin=128 ----
        int n0 = blockIdx.x * 128;
        const u16* xb = sr_t + (size_t)b * NN * C;
        f32x16 acc[2][2];
#pragma unroll
        for (int xt = 0; xt < 2; xt++)
#pragma unroll
            for (int wt2 = 0; wt2 < 2; wt2++)
#pragma unroll
                for (int i = 0; i < 16; i++) acc[xt][wt2][i] = 0.f;
        for (int c0i = 0; c0i < 2; c0i++) {
            int c0 = c0i * 64;
            __syncthreads();
#pragma unroll
            for (int t = 0; t < 4; t++) {
                int CI = t * 256 + tid;
                int row = CI >> 3, sl = CI & 7;
                int lc = sl ^ (row & 7);
                __builtin_amdgcn_global_load_lds(
                    (const __attribute__((address_space(1))) void*)(xb + (size_t)(n0 + row) * C + c0 + lc * 8),
                    (__attribute__((address_space(3))) void*)&xs[(size_t)CI * 8], 16, 0, 0);
            }
#pragma unroll
            for (int t = 0; t < 4; t++) {
                int CI = t * 256 + tid;
                int co = CI >> 3, sl = CI & 7;
                int lc = sl ^ (co & 7);
                __builtin_amdgcn_global_load_lds(
                    (const __attribute__((address_space(1))) void*)(wbf + (size_t)co * C + c0 + lc * 8),
                    (__attribute__((address_space(3))) void*)&wsm[0][(size_t)CI * 8], 16, 0, 0);
            }
            __syncthreads();
#pragma unroll
            for (int kg = 0; kg < 4; kg++) {
                int pc = ((kg * 2 + half) ^ (l31 & 7)) * 8;
                s16x8 xf[2], wf2[2];
#pragma unroll
                for (int xt = 0; xt < 2; xt++)
                    xf[xt] = *(const s16x8*)&xs[(xh * 64 + xt * 32 + l31) * 64 + pc];
#pragma unroll
                for (int wt2 = 0; wt2 < 2; wt2++)
                    wf2[wt2] = *(const s16x8*)&wsm[0][(wh * 64 + wt2 * 32 + l31) * 64 + pc];
#pragma unroll
                for (int xt = 0; xt < 2; xt++)
#pragma unroll
                    for (int wt2 = 0; wt2 < 2; wt2++)
                        acc[xt][wt2] = __builtin_amdgcn_mfma_f32_32x32x16_bf16(xf[xt], wf2[wt2], acc[xt][wt2], 0, 0, 0);
            }
        }
        u16* ot = q_t + (size_t)b * NN * C;
        float bv2[2];
#pragma unroll
        for (int wt2 = 0; wt2 < 2; wt2++) bv2[wt2] = bq[wh * 64 + wt2 * 32 + l31] * LOG2E;
#pragma unroll
        for (int xt = 0; xt < 2; xt++)
#pragma unroll
            for (int r = 0; r < 16; r++) {
                int n = n0 + xh * 64 + xt * 32 + (r & 3) + 8 * (r >> 2) + 4 * half;
#pragma unroll
                for (int wt2 = 0; wt2 < 2; wt2++)
                    ot[(size_t)n * C + wh * 64 + wt2 * 32 + l31] = f2bf(acc[xt][wt2][r] + bv2[wt2]);
            }
    } else {
        // ---- K & V: 64 source px x 128 co, Cin=256, ctx staged once ----
        int n0 = (blockIdx.x - 32) * 64;
        const u16* xb = ctx_s + (size_t)b * NS * CCH;
        const u16* wkb = wbf + 16384;
        const u16* wvb = wbf + 49152;
        f32x16 acck[2], accv[2];   // [wt2]; wave: n-tile xh*32, co wh*64+wt2*32
#pragma unroll
        for (int wt2 = 0; wt2 < 2; wt2++)
#pragma unroll
            for (int i = 0; i < 16; i++) { acck[wt2][i] = 0.f; accv[wt2][i] = 0.f; }
        for (int c0i = 0; c0i < 4; c0i++) {
            int c0 = c0i * 64;
            __syncthreads();
#pragma unroll
            for (int t = 0; t < 2; t++) {          // 64 rows x 8 chunks
                int CI = t * 256 + tid;
                int row = CI >> 3, sl = CI & 7;
                int lc = sl ^ (row & 7);
                __builtin_amdgcn_global_load_lds(
                    (const __attribute__((address_space(1))) void*)(xb + (size_t)(n0 + row) * CCH + c0 + lc * 8),
                    (__attribute__((address_space(3))) void*)&xs[(size_t)CI * 8], 16, 0, 0);
            }
#pragma unroll
            for (int t = 0; t < 4; t++) {
                int CI = t * 256 + tid;
                int co = CI >> 3, sl = CI & 7;
                int lc = sl ^ (co & 7);
                __builtin_amdgcn_global_load_lds(
                    (const __attribute__((address_space(1))) void*)(wkb + (size_t)co * CCH + c0 + lc * 8),
                    (__attribute__((address_space(3))) void*)&wsm[0][(size_t)CI * 8], 16, 0, 0);
            }
#pragma unroll
            for (int t = 0; t < 4; t++) {
                int CI = t * 256 + tid;
                int co = CI >> 3, sl = CI & 7;
                int lc = sl ^ (co & 7);
                __builtin_amdgcn_global_load_lds(
                    (const __attribute__((address_space(1))) void*)(wvb + (size_t)co * CCH + c0 + lc * 8),
                    (__attribute__((address_space(3))) void*)&wsm[1][(size_t)CI * 8], 16, 0, 0);
            }
            __syncthreads();
#pragma unroll
            for (int kg = 0; kg < 4; kg++) {
                int pc = ((kg * 2 + half) ^ (l31 & 7)) * 8;
                s16x8 xf = *(const s16x8*)&xs[(xh * 32 + l31) * 64 + pc];
                s16x8 wfk[2], wfv[2];
#pragma unroll
                for (int wt2 = 0; wt2 < 2; wt2++) {
                    wfk[wt2] = *(const s16x8*)&wsm[0][(wh * 64 + wt2 * 32 + l31) * 64 + pc];
                    wfv[wt2] = *(const s16x8*)&wsm[1][(wh * 64 + wt2 * 32 + l31) * 64 + pc];
                }
#pragma unroll
                for (int wt2 = 0; wt2 < 2; wt2++) {
                    acck[wt2] = __builtin_amdgcn_mfma_f32_32x32x16_bf16(xf, wfk[wt2], acck[wt2], 0, 0, 0);
                    accv[wt2] = __builtin_amdgcn_mfma_f32_32x32x16_bf16(wfv[wt2], xf, accv[wt2], 0, 0, 0);
                }
            }
        }
        // K epilogue: T-layout k_s[b][n][co]
        u16* ok = k_s + (size_t)b * NS * C;
#pragma unroll
        for (int wt2 = 0; wt2 < 2; wt2++) {
            float bvk = bk[wh * 64 + wt2 * 32 + l31];
#pragma unroll
            for (int r = 0; r < 16; r++) {
                int n = n0 + xh * 32 + (r & 3) + 8 * (r >> 2) + 4 * half;
                ok[(size_t)n * C + wh * 64 + wt2 * 32 + l31] = f2bf(acck[wt2][r] + bvk);
            }
        }
        // V epilogue: N-layout v_s[b][co][n]
        u16* ov = v_s + (size_t)b * C * NS;
#pragma unroll
        for (int wt2 = 0; wt2 < 2; wt2++)
#pragma unroll
            for (int r = 0; r < 16; r++) {
                int co = wh * 64 + wt2 * 32 + (r & 3) + 8 * (r >> 2) + 4 * half;
                ov[(size_t)co * NS + n0 + xh * 32 + l31] = f2bf(accv[wt2][r] + bv[co]);
            }
    }
}

// ---------------------------------------------------------------------------
// 3) upsample_kv: [0,256) k_s [b][1024][C] -> k_t [b][4096][C]
//                 [256,768) v_s [b][C][1024] -> v [b][C][4096]
//    (bilinear, half-pixel centers, clamped — commutes with 1x1 conv)
// ---------------------------------------------------------------------------
__global__ __launch_bounds__(256) void upsample_kv(const u16* __restrict__ k_s,
                                                   const u16* __restrict__ v_s,
                                                   u16* __restrict__ k_t,
                                                   u16* __restrict__ v_bf) {
    __shared__ u16 lsv[NS];
    int blk = blockIdx.x;
    int tid = threadIdx.x;
    if (blk < 256) {
        // one output row y (64 px), all 128 ch
        int y = blk & 63, b = blk >> 6;
        float sy = y * 0.5f - 0.25f;
        int y0 = (int)floorf(sy);
        float wy = sy - (float)y0;
        int y0c = y0 < 0 ? 0 : y0;
        int y1c = (y0 + 1 > HC - 1) ? HC - 1 : y0 + 1;
        int occ = tid & 127, xh = tid >> 7;
        const u16* kb = k_s + (size_t)b * NS * C;
        u16* ob = k_t + ((size_t)b * NN + (size_t)y * 64) * C + occ;
        float wy1 = 1.f - wy;
#pragma unroll
        for (int xi = 0; xi < 32; xi++) {
            int x = xi * 2 + xh;
            float sx = x * 0.5f - 0.25f;
            int x0 = (int)floorf(sx);
            float wx = sx - (float)x0;
            int x0c = x0 < 0 ? 0 : x0;
            int x1c = (x0 + 1 > WC - 1) ? WC - 1 : x0 + 1;
            float v00 = bf2f(kb[(size_t)(y0c * WC + x0c) * C + occ]);
            float v01 = bf2f(kb[(size_t)(y0c * WC + x1c) * C + occ]);
            float v10 = bf2f(kb[(size_t)(y1c * WC + x0c) * C + occ]);
            float v11 = bf2f(kb[(size_t)(y1c * WC + x1c) * C + occ]);
            float val = wy1 * ((1.f - wx) * v00 + wx * v01)
                      + wy  * ((1.f - wx) * v10 + wx * v11);
            ob[(size_t)x * C] = f2bf(val);
        }
    } else {
        // one (b,c) plane: 1024 -> 4096
        int idx = blk - 256;
        int c = idx & 127, b = idx >> 7;
        const u16* vp = v_s + ((size_t)b * C + c) * NS;
        if (tid < 128) *(uint4*)&lsv[tid * 8] = *(const uint4*)(vp + tid * 8);
        __syncthreads();
        u16* ob = v_bf + ((size_t)b * C + c) * NN;
#pragma unroll
        for (int j = 0; j < 16; j++) {
            int n = tid + j * 256;
            int y = n >> 6, x = n & 63;
            float sy = y * 0.5f - 0.25f;
            float sx = x * 0.5f - 0.25f;
            int y0 = (int)floorf(sy), x0 = (int)floorf(sx);
            float wy = sy - (float)y0, wx = sx - (float)x0;
            int y0c = y0 < 0 ? 0 : y0;
            int y1c = (y0 + 1 > HC - 1) ? HC - 1 : y0 + 1;
            int x0c = x0 < 0 ? 0 : x0;
            int x1c = (x0 + 1 > WC - 1) ? WC - 1 : x0 + 1;
            float v00 = bf2f(lsv[y0c * WC + x0c]), v01 = bf2f(lsv[y0c * WC + x1c]);
            float v10 = bf2f(lsv[y1c * WC + x0c]), v11 = bf2f(lsv[y1c * WC + x1c]);
            ob[n] = f2bf((1.f - wy) * ((1.f - wx) * v00 + wx * v01)
                       +        wy  * ((1.f - wx) * v10 + wx * v11));
        }
    }
}

// ---------------------------------------------------------------------------
// 4) Flash attention v10 (unchanged, proven 50 us).
// ---------------------------------------------------------------------------
__global__ __launch_bounds__(256) void flash_mfma(const u16* __restrict__ qt_p,
                                                  const u16* __restrict__ kt_p,
                                                  const u16* __restrict__ vt_p,
                                                  u16* __restrict__ part,
                                                  float* __restrict__ lpart) {
    __shared__ u16 ks[2][64 * 128];
    __shared__ u16 vs[2][128 * 64];

    int ib = blockIdx.x;
    int b = (ib & 7) >> 1;
    int rest = ((ib >> 3) << 1) | (ib & 1);
    int qtile = rest >> 2;
    int split = rest & 3;
    int n0 = qtile * 128;
    int tid = threadIdx.x;
    int w = tid >> 6, lane = tid & 63, l31 = lane & 31, half = lane >> 5;

    const u16* qtb = qt_p + (size_t)b * NN * C;
    const u16* ktb = kt_p + (size_t)b * NN * C;
    const u16* vtb = vt_p + (size_t)b * C * NN;

    auto stageK = [&](int buf, int m0) {
#pragma unroll
        for (int t = 0; t < 4; t++) {
            int CI = (w * 4 + t) * 64 + lane;
            int r = CI >> 4;
            int lc = (CI & 15) ^ (r & 15);
            __builtin_amdgcn_global_load_lds(
                (const __attribute__((address_space(1))) void*)(ktb + (size_t)(m0 + r) * C + lc * 8),
                (__attribute__((address_space(3))) void*)&ks[buf][(w * 4 + t) * 512], 16, 0, 0);
        }
    };
    auto stageV = [&](int buf, int m0) {
#pragma unroll
        for (int t = 0; t < 4; t++) {
            int CI = (w * 4 + t) * 64 + lane;
            int c = CI >> 3;
            int lc = (CI & 7) ^ (c & 7);
            __builtin_amdgcn_global_load_lds(
                (const __attribute__((address_space(1))) void*)(vtb + (size_t)c * NN + m0 + lc * 8),
                (__attribute__((address_space(3))) void*)&vs[buf][(w * 4 + t) * 512], 16, 0, 0);
        }
    };

    int qrow = n0 + w * 32 + l31;
    s16x8 qf[8];
#pragma unroll
    for (int kg = 0; kg < 8; kg++)
        qf[kg] = *(const s16x8*)(qtb + (size_t)qrow * C + kg * 16 + half * 8);

    int m_base = split * 1024;
    stageK(0, m_base);
    stageV(0, m_base);
    __syncthreads();

    f32x16 oacc[4];
#pragma unroll
    for (int mt = 0; mt < 4; mt++)
#pragma unroll
        for (int i = 0; i < 16; i++) oacc[mt][i] = 0.f;
    float lsum = 0.f;

    for (int it = 0; it < 16; it++) {
        int buf = it & 1;
        int m0 = m_base + it * 64;
        if (it < 15) {
            stageK(buf ^ 1, m0 + 64);
            stageV(buf ^ 1, m0 + 64);
        }
        const u16* ksb = &ks[buf][0];
        const u16* vsb = &vs[buf][0];

#pragma unroll
        for (int kmt = 0; kmt < 2; kmt++) {
            f32x16 st;
#pragma unroll
            for (int i = 0; i < 16; i++) st[i] = 0.f;
#pragma unroll
            for (int kg = 0; kg < 8; kg++) {
                int pc = ((kg * 2 + half) ^ (l31 & 15)) * 8;
                s16x8 kf = *(const s16x8*)&ksb[(kmt * 32 + l31) * 128 + pc];
                st = __builtin_amdgcn_mfma_f32_32x32x16_bf16(kf, qf[kg], st, 0, 0, 0);
            }
            uint32 A[4], B4[4];
#pragma unroll
            for (int rg = 0; rg < 4; rg++) {
                float e0 = EXP2(st[rg * 4 + 0]);
                float e1 = EXP2(st[rg * 4 + 1]);
                float e2 = EXP2(st[rg * 4 + 2]);
                float e3 = EXP2(st[rg * 4 + 3]);
                lsum += (e0 + e1) + (e2 + e3);
                A[rg]  = __builtin_amdgcn_perm(__float_as_uint(e1), __float_as_uint(e0), 0x07060302u);
                B4[rg] = __builtin_amdgcn_perm(__float_as_uint(e3), __float_as_uint(e2), 0x07060302u);
            }
#pragma unroll
            for (int s = 0; s < 2; s++) {
                uint32 sendA = half ? A[2 * s] : A[2 * s + 1];
                uint32 sendB = half ? B4[2 * s] : B4[2 * s + 1];
                uint32 rA = __shfl_xor(sendA, 32);
                uint32 rB = __shfl_xor(sendB, 32);
                uint32 oA = half ? A[2 * s + 1] : A[2 * s];
                uint32 oB = half ? B4[2 * s + 1] : B4[2 * s];
                union { uint32 u[4]; s16x8 v; } pu;
                pu.u[0] = half ? rA : oA;
                pu.u[1] = half ? rB : oB;
                pu.u[2] = half ? oA : rA;
                pu.u[3] = half ? oB : rB;
                s16x8 pf = pu.v;
                int kgp = kmt * 2 + s;
                int pcv = ((kgp * 2 + half) ^ (l31 & 7)) * 8;
#pragma unroll
                for (int mt = 0; mt < 4; mt++) {
                    s16x8 vf = *(const s16x8*)&vsb[(mt * 32 + l31) * 64 + pcv];
                    oacc[mt] = __builtin_amdgcn_mfma_f32_32x32x16_bf16(vf, pf, oacc[mt], 0, 0, 0);
                }
            }
        }
        __syncthreads();
    }

    float lt = lsum + __shfl_xor(lsum, 32);
    if (half == 0) lpart[(size_t)split * NB * NN + (size_t)b * NN + qrow] = lt;
    u16* pb = part + ((size_t)split * NB + b) * (size_t)C * NN;
#pragma unroll
    for (int mt = 0; mt < 4; mt++)
#pragma unroll
        for (int r = 0; r < 16; r++) {
            int c = mt * 32 + (r & 3) + 8 * (r >> 2) + 4 * half;
            pb[(size_t)c * NN + n0 + w * 32 + l31] = f2bf(oacc[mt][r]);
        }
}

// ---------------------------------------------------------------------------
// 5) Combine (unchanged).
// ---------------------------------------------------------------------------
__global__ __launch_bounds__(256) void flash_combine(const u16* __restrict__ part,
                                                     const float* __restrict__ lpart,
                                                     u16* __restrict__ att_t) {
    __shared__ u16 ts[128 * 66];
    __shared__ float linv[64];
    int b = blockIdx.y;
    int nt = blockIdx.x;
    int n0 = nt * 64;
    int tid = threadIdx.x;
    if (tid < 64) {
        float s = 0.f;
#pragma unroll
        for (int sp = 0; sp < NSPLIT; sp++)
            s += lpart[(size_t)sp * NB * NN + (size_t)b * NN + n0 + tid];
        linv[tid] = 1.0f / s;
    }
    __syncthreads();
#pragma unroll
    for (int j = 0; j < 32; j++) {
        int e = tid + j * 256;
        int n = e & 63, c = e >> 6;
        float o = 0.f;
#pragma unroll
        for (int sp = 0; sp < NSPLIT; sp++)
            o += bf2f(part[((size_t)sp * NB + b) * (size_t)C * NN + (size_t)c * NN + n0 + n]);
        ts[c * 66 + n] = f2bf(o * linv[n]);
    }
    __syncthreads();
    u16* ob = att_t + ((size_t)b * PP * PP + (size_t)(nt + 1) * PP + 1) * C;
#pragma unroll
    for (int j = 0; j < 32; j++) {
        int o = tid + j * 256;
        int c = o & 127, n = o >> 7;
        ob[(size_t)n * C + c] = ts[c * 66 + n];
    }
}

// ---------------------------------------------------------------------------
// 6) Conv3x3 MFMA + residual (unchanged).
// ---------------------------------------------------------------------------
__global__ __launch_bounds__(256) void conv3x3_mfma(const u16* __restrict__ att_t,
                                                    const u16* __restrict__ wt,
                                                    const float* __restrict__ bp,
                                                    const float* __restrict__ sr,
                                                    const float* __restrict__ gamma,
                                                    float* __restrict__ out) {
    __shared__ u16 in_s[2][4 * 102 * 8];
    int ib = blockIdx.x;
    int b = (ib & 7) >> 1;
    int rr = ((ib >> 3) << 1) | (ib & 1);
    int y = rr >> 1;
    int x0 = (rr & 1) * 32;
    int tid = threadIdx.x;
    int w = tid >> 6, lane = tid & 63, l = tid & 15, quad = (tid >> 4) & 3;
    const u16* ab = att_t + (size_t)b * (PP * PP * C);

    auto stage = [&](int cib, int bufi) {
        u16* base = &in_s[bufi][w * 102 * 8];
        const u16* gsrc = ab + cib * 32 + w * 8;
#pragma unroll
        for (int t = 0; t < 2; t++) {
            int idx = t * 64 + lane;
            int r = idx / 34, xp = idx - r * 34;
            if (t == 0 || lane < 38)
                __builtin_amdgcn_global_load_lds(
                    (const __attribute__((address_space(1))) void*)(gsrc + (size_t)((y + r) * PP + x0 + xp) * C),
                    (__attribute__((address_space(3))) void*)(base + (size_t)t * 64 * 8), 16, 0, 0);
        }
    };

    f32x4 accr[2][2];
#pragma unroll
    for (int cf = 0; cf < 2; cf++)
#pragma unroll
        for (int nf = 0; nf < 2; nf++) accr[cf][nf] = (f32x4){0.f, 0.f, 0.f, 0.f};
    int cow = w * 32;

    stage(0, 0);
    __syncthreads();
#pragma unroll
    for (int cib = 0; cib < 4; cib++) {
        if (cib < 3) stage(cib + 1, (cib + 1) & 1);
        s16x8 wf[9][2];
#pragma unroll
        for (int pos = 0; pos < 9; pos++)
#pragma unroll
            for (int cf = 0; cf < 2; cf++)
                wf[pos][cf] = *(const s16x8*)&wt[((size_t)(pos * 4 + cib) * C + cow + cf * 16 + l) * 32 + quad * 8];
        const u16* bufc = &in_s[cib & 1][0];
#pragma unroll
        for (int ky = 0; ky < 3; ky++)
#pragma unroll
            for (int kx = 0; kx < 3; kx++) {
                int pos = ky * 3 + kx;
#pragma unroll
                for (int nf = 0; nf < 2; nf++) {
                    s16x8 inf = *(const s16x8*)&bufc[(quad * 102 + ky * 34 + nf * 16 + l + kx) * 8];
                    accr[0][nf] = __builtin_amdgcn_mfma_f32_16x16x32_bf16(wf[pos][0], inf, accr[0][nf], 0, 0, 0);
                    accr[1][nf] = __builtin_amdgcn_mfma_f32_16x16x32_bf16(wf[pos][1], inf, accr[1][nf], 0, 0, 0);
                }
            }
        __syncthreads();
    }

    float g = gamma[0];
    float* ob = out + (size_t)b * C * NN;
    const float* sb = sr + (size_t)b * C * NN;
#pragma unroll
    for (int cf = 0; cf < 2; cf++)
#pragma unroll
        for (int r = 0; r < 4; r++) {
            int co = cow + cf * 16 + quad * 4 + r;
            float bias = bp[co];
#pragma unroll
            for (int nf = 0; nf < 2; nf++) {
                size_t oo = (size_t)co * NN + y * 64 + x0 + nf * 16 + l;
                ob[oo] = sb[oo] + g * (accr[cf][nf][r] + bias);
            }
        }
}

// ---------------------------------------------------------------------------
extern "C" void kernel_launch(void* const* d_in, const int* in_sizes, int n_in,
                              void* d_out, int out_size, void* d_ws, size_t ws_size,
                              hipStream_t stream) {
    const float* sr    = (const float*)d_in[0];
    const float* ctx   = (const float*)d_in[1];
    const float* Wq    = (const float*)d_in[2];
    const float* bq    = (const float*)d_in[3];
    const float* Wk    = (const float*)d_in[4];
    const float* bk    = (const float*)d_in[5];
    const float* Wv    = (const float*)d_in[6];
    const float* bv    = (const float*)d_in[7];
    const float* Wp    = (const float*)d_in[8];
    const float* bp    = (const float*)d_in[9];
    const float* gamma = (const float*)d_in[10];
    float* out = (float*)d_out;

    // ws layout (MB): att_t@0 | part@5 (16MB) | lpart@21 | ctx_s@22 (2MB) |
    //   sr_t@25 (4MB) | q_t@29 (4MB) | k_s@33 (1MB) | v_s@34 (1MB) |
    //   k_t@35 (4MB) | v@39 (4MB) | wt@43 | w_bf@43.5
    char* wsb = (char*)d_ws;
    u16*   att_t  = (u16*)wsb;
    u16*   part   = (u16*)(wsb + (5u << 20));
    float* lpart  = (float*)(wsb + (21u << 20));
    u16*   ctx_s  = (u16*)(wsb + (22u << 20));
    u16*   sr_t   = (u16*)(wsb + (25u << 20));
    u16*   q_t    = (u16*)(wsb + (29u << 20));
    u16*   k_s    = (u16*)(wsb + (33u << 20));
    u16*   v_s    = (u16*)(wsb + (34u << 20));
    u16*   k_t    = (u16*)(wsb + (35u << 20));
    u16*   v_bf   = (u16*)(wsb + (39u << 20));
    u16*   wt     = (u16*)(wsb + (43u << 20));
    u16*   w_bf   = (u16*)(wsb + (43u << 20) + (512u << 10));

    prep2<<<dim3(2753), 256, 0, stream>>>(ctx, sr, Wq, Wk, Wv, Wp,
                                          ctx_s, sr_t, w_bf, wt, (uint4*)att_t);
    proj_all2<<<dim3(48, NB), 256, 0, stream>>>(sr_t, ctx_s, w_bf, bq, bk, bv,
                                                q_t, k_s, v_s);
    upsample_kv<<<dim3(768), 256, 0, stream>>>(k_s, v_s, k_t, v_bf);
    flash_mfma<<<dim3(512), 256, 0, stream>>>(q_t, k_t, v_bf, part, lpart);
    flash_combine<<<dim3(64, NB), 256, 0, stream>>>(part, lpart, att_t);
    conv3x3_mfma<<<dim3(512), 256, 0, stream>>>(att_t, wt, bp, sr, gamma, out);
}